// Round 10
// baseline (1146.521 us; speedup 1.0000x reference)
//
#include <hip/hip_runtime.h>
#include <hip/hip_bf16.h>
#include <stdint.h>

// PhaseUPDeT fused forward — round 12: LDS XOR chunk-swizzle (register-neutral).
// All stride-144 b16 scatter stores (Q/K/X/T1) have quarter-wave row-step
// 4*144B = 144 dwords = 16 mod 32 -> quarters {0,2} and {1,3} alias on the
// same 8-bank windows = 4-way conflict (6.5% of CU-cycles at 2.2e7).
// Fix: chunk swizzle off ^= ((row>>1)&7)<<4 (144-stride) and
// off ^= (((row>>1)&3)^((row>>2)&2))<<4 (P, stride 80) — verified by
// tabulation to put the 4 quarter-waves on 4 disjoint 8-bank windows.
// Bijective, alignment-preserving, zero LDS/register cost. Base = 488 µs
// round-11; only LDS address expressions changed.

typedef __hip_bfloat16 bf16;
using bf16x8 = __attribute__((ext_vector_type(8))) short;
using f32x4  = __attribute__((ext_vector_type(4))) float;
using s16x4  = __attribute__((ext_vector_type(4))) short;

#define BTOT 8192
#define SCL 0.35355339059327373f

// hand-rolled RNE (prep kernel only; runs once, perf-irrelevant)
__device__ __forceinline__ short f2bf(float f) {
  uint32_t u = __float_as_uint(f);
  return (short)((u + 0x7FFFu + ((u >> 16) & 1u)) >> 16);
}
__device__ __forceinline__ float bf2f(short s) {
  return __uint_as_float(((uint32_t)(uint16_t)s) << 16);
}
// f32 -> bf16 via official API: RNE, lowered by clang to the HW convert.
__device__ __forceinline__ short f2bfh(float f) {
  __hip_bfloat16 h = __float2bfloat16(f);
  return *reinterpret_cast<short*>(&h);
}
__device__ __forceinline__ f32x4 MM(bf16x8 a, bf16x8 b, f32x4 c) {
  return __builtin_amdgcn_mfma_f32_16x16x32_bf16(a, b, c, 0, 0, 0);
}
// chunk swizzle for stride-144 buffers (X/Q/K/T1): off in [0,128)
__device__ __forceinline__ int sw(int row, int off) {
  return off ^ (((row >> 1) & 7) << 4);
}
// chunk swizzle for P (stride 80): off in [0,64)
__device__ __forceinline__ int swp(int row, int off) {
  return off ^ ((((row >> 1) & 3) ^ ((row >> 2) & 2)) << 4);
}

// ---------------- LDS layout (bytes) ----------------
#define OFF_X   0
#define OFF_Q   11520
#define OFF_K   23184
#define OFF_VT  34848
#define OFF_V32 45088
#define OFF_P   45344
#define OFF_T1  34848
#define OFF_ZZ1 46368
#define OFF_ZZ2 47392
#define OFF_PB  47904
#define OFF_PR  47968
#define OFF_PHB 53024
#define SMEM_SZ 53280

// ws fragment-slot offsets (units of bf16x8 = 8 elems)
#define WS_EMB 0
#define WS_WQ  256
#define WS_WK  4352
#define WS_WV  8448
#define WS_WU  12544
#define WS_W1  16640
#define WS_W2  20736
#define WS_TOP 24832
#define WS_BYTES 405504

__device__ __forceinline__ bf16x8 LD8(const uint8_t* sm, int off) {
  return *(const bf16x8*)(sm + off);
}
__device__ __forceinline__ void ST16(uint8_t* sm, int off, short v) {
  *(short*)(sm + off) = v;
}
__device__ __forceinline__ short LD16(const uint8_t* sm, int off) {
  return *(const short*)(sm + off);
}

// ---------------- prep kernel ----------------
struct PP {
  const float *emb, *wq, *wk, *wvp, *wu, *w1, *w2, *top;
  short* dst;
};

__global__ __launch_bounds__(256) void prep_frags(PP pp) {
  constexpr int START[15] = {0, 2048, 18432, 34816, 51200, 67584, 83968,
                             100352, 116736, 133120, 149504, 165888, 182272,
                             198656, 202752};
  for (int idx = blockIdx.x * 256 + threadIdx.x; idx < 202752;
       idx += gridDim.x * 256) {
#pragma unroll
    for (int t = 0; t < 14; ++t) {
      if (idx >= START[t] && idx < START[t + 1]) {
        int K, N; const float* s; float sc = 1.0f;
        switch (t) {
          case 0:  s = pp.emb;          K = 32;  N = 64;  break;
          case 1:  s = pp.wq;           K = 64;  N = 256; sc = SCL; break;
          case 2:  s = pp.wq + 16384;   K = 64;  N = 256; sc = SCL; break;
          case 3:  s = pp.wk;           K = 64;  N = 256; sc = SCL; break;
          case 4:  s = pp.wk + 16384;   K = 64;  N = 256; sc = SCL; break;
          case 5:  s = pp.wvp;          K = 64;  N = 256; break;
          case 6:  s = pp.wvp + 16384;  K = 64;  N = 256; break;
          case 7:  s = pp.wu;           K = 256; N = 64;  break;
          case 8:  s = pp.wu + 16384;   K = 256; N = 64;  break;
          case 9:  s = pp.w1;           K = 64;  N = 256; break;
          case 10: s = pp.w1 + 16384;   K = 64;  N = 256; break;
          case 11: s = pp.w2;           K = 256; N = 64;  break;
          case 12: s = pp.w2 + 16384;   K = 256; N = 64;  break;
          default: s = pp.top;          K = 64;  N = 64;  break;
        }
        int rel = idx - START[t];
        int lane = (rel >> 3) & 63, jj = rel & 7, fi = rel >> 9;
        int KS = K >> 5;
        int nt = fi / KS, ks = fi - nt * KS;
        int k = ks * 32 + ((lane >> 4) << 3) + jj;
        int n = nt * 16 + (lane & 15);
        pp.dst[idx] = f2bf(s[(size_t)k * N + n] * sc);
      }
    }
  }
}

// ---------------- main kernel ----------------
struct MP {
  const float *inputs, *hidden, *p_h;
  const float *emb_b, *bu, *ln1_g, *ln1_b, *ff_b1, *ff_b2, *ln2_g, *ln2_b,
      *toprobs_b;
  const float *cls_W1, *cls_b1, *cls_W2, *cls_b2, *cls_W3, *cls_b3;
  const float *qself_W, *qself_b, *qint_W, *qint_b, *p_e_w;
  const bf16x8* ws;
  float* out;
};

__global__ __launch_bounds__(512, 4) void fused_mfma(MP p) {
  __shared__ __align__(16) uint8_t sm[SMEM_SZ];
  const int tid = threadIdx.x;
  const int lane = tid & 63;
  const int wv = tid >> 6;  // 0..7
  const int g16 = lane >> 4;
  const int l15 = lane & 15;
  const int b0 = blockIdx.x * 2;
  const bf16x8* WS = p.ws;

  // ---- stage p_h, inputs (bf16, stride 40 @ OFF_T1, linear), hidden ----
  if (tid < 64) {
    *(float*)(sm + OFF_PHB + tid * 4) =
        p.p_h[(size_t)(b0 + (tid >> 5)) * 32 + (tid & 31)];
  }
  for (int idx = tid; idx < 2048; idx += 512) {
    int r = idx >> 5, c = idx & 31;
    ST16(sm, OFF_T1 + r * 80 + c * 2, f2bfh(p.inputs[(size_t)b0 * 1024 + idx]));
  }
  if (tid < 128) {
    int e = tid >> 6, c = tid & 63;
    int hrow = e * 33 + 32;
    ST16(sm, OFF_X + hrow * 144 + sw(hrow, c * 2),
         f2bfh(p.hidden[(size_t)(b0 + e) * 64 + c]));
  }
  __syncthreads();

  // ---- emb GEMM: 16 (mt,nt) units over 8 waves ----
  {
#pragma unroll
    for (int uu = 0; uu < 2; ++uu) {
      int u = wv * 2 + uu;
      int mt = u >> 2, nt = u & 3;
      int arow = mt * 16 + l15;
      bf16x8 a = LD8(sm, OFF_T1 + arow * 80 + g16 * 16);
      int col = nt * 16 + l15;
      float eb = p.emb_b[col];
      f32x4 acc = {eb, eb, eb, eb};
      acc = MM(a, WS[WS_EMB + nt * 64 + lane], acc);
#pragma unroll
      for (int i = 0; i < 4; ++i) {
        int r = mt * 16 + g16 * 4 + i;
        int grow = (r >> 5) * 33 + (r & 31);
        ST16(sm, OFF_X + grow * 144 + sw(grow, col * 2), f2bfh(acc[i]));
      }
    }
  }
  __syncthreads();

  // attention-core ownership: wave wv<6 owns (elem ea, M-tile mtl)
  const bool att = wv < 6;
  const int ea = wv & 1;
  const int mtl = wv >> 1;  // 0..2 when att
  const int e33 = ea * 33;

  for (int L = 0; L < 2; ++L) {
    const int wq8 = WS_WQ + L * 2048, wk8 = WS_WK + L * 2048,
              wv8 = WS_WV + L * 2048, wu8 = WS_WU + L * 2048,
              w18 = WS_W1 + L * 2048, w28 = WS_W2 + L * 2048;

    // Wu accumulators (persist across heads), init with bu
    f32x4 wu[4];
#pragma unroll
    for (int nt = 0; nt < 4; ++nt) {
      float bv = p.bu[L * 64 + nt * 16 + l15];
      wu[nt] = {bv, bv, bv, bv};
    }

    for (int h = 0; h < 4; ++h) {
      // ---- QKV for head h: flat split over 20 (mt,nt) pairs, 8 waves ----
      for (int wid = wv; wid < 20; wid += 8) {
        int mt = wid >> 2, nt = wid & 3;
        int arow = mt * 16 + l15;
        bf16x8 a0 = LD8(sm, OFF_X + arow * 144 + sw(arow, g16 * 16));
        bf16x8 a1 = LD8(sm, OFF_X + arow * 144 + sw(arow, 64 + g16 * 16));
        int col = nt * 16 + l15;
        int rb = mt * 16 + g16 * 4;
        int f0 = (h * 4 + nt) * 2;
        f32x4 q = {0.f, 0.f, 0.f, 0.f}, k = q, v = q;
        q = MM(a0, WS[wq8 + f0 * 64 + lane], q);
        q = MM(a1, WS[wq8 + (f0 + 1) * 64 + lane], q);
        k = MM(a0, WS[wk8 + f0 * 64 + lane], k);
        k = MM(a1, WS[wk8 + (f0 + 1) * 64 + lane], k);
        v = MM(a0, WS[wv8 + f0 * 64 + lane], v);
        v = MM(a1, WS[wv8 + (f0 + 1) * 64 + lane], v);
#pragma unroll
        for (int i = 0; i < 4; ++i) {
          int r = rb + i;
          if (r < 66) {
            ST16(sm, OFF_Q + r * 144 + sw(r, col * 2), f2bfh(q[i]));
            ST16(sm, OFF_K + r * 144 + sw(r, col * 2), f2bfh(k[i]));
          }
        }
        // v transposed: VT[(e*64+col)][tok]; packed b64 on the aligned path
        if (rb <= 28) {  // e=0, toks rb..rb+3, 8B-aligned
          s16x4 pv = {f2bfh(v[0]), f2bfh(v[1]), f2bfh(v[2]), f2bfh(v[3])};
          *(s16x4*)(sm + OFF_VT + col * 80 + rb * 2) = pv;
        } else if (rb >= 36 && rb <= 60) {  // e=1, toks rb-33.. (2B-aligned)
          int vb = OFF_VT + (64 + col) * 80 + (rb - 33) * 2;
          ST16(sm, vb, f2bfh(v[0]));
          ST16(sm, vb + 2, f2bfh(v[1]));
          ST16(sm, vb + 4, f2bfh(v[2]));
          ST16(sm, vb + 6, f2bfh(v[3]));
        } else if (rb == 32) {  // r=32: e0 tok32 -> V32; r=33..35: e1 tok0..2
          ST16(sm, OFF_V32 + col * 2, f2bfh(v[0]));
          int vb = OFF_VT + (64 + col) * 80;
          ST16(sm, vb, f2bfh(v[1]));
          ST16(sm, vb + 2, f2bfh(v[2]));
          ST16(sm, vb + 4, f2bfh(v[3]));
        } else if (rb == 64) {  // r=64: e1 tok31; r=65: e1 tok32 -> V32
          ST16(sm, OFF_VT + (64 + col) * 80 + 31 * 2, f2bfh(v[0]));
          ST16(sm, OFF_V32 + (64 + col) * 2, f2bfh(v[1]));
        }
      }
      __syncthreads();

      if (att) {
        // ---- scores: one (ea, mtl) tile per wave ----
        f32x4 S[3];
        {
          int arow = e33 + mtl * 16 + l15;
          bf16x8 a0 = LD8(sm, OFF_Q + arow * 144 + sw(arow, g16 * 16));
          bf16x8 a1 = LD8(sm, OFF_Q + arow * 144 + sw(arow, 64 + g16 * 16));
#pragma unroll
          for (int nt = 0; nt < 3; ++nt) {
            int brow = e33 + nt * 16 + l15;
            bf16x8 kb0 = LD8(sm, OFF_K + brow * 144 + sw(brow, g16 * 16));
            bf16x8 kb1 = LD8(sm, OFF_K + brow * 144 + sw(brow, 64 + g16 * 16));
            f32x4 acc = {0.f, 0.f, 0.f, 0.f};
            acc = MM(a0, kb0, acc);
            acc = MM(a1, kb1, acc);
            S[nt] = acc;
          }
        }
        // ---- softmax, no-max variant (scores O(1); shift-invariant) ----
        // Store RAW exp to P (swizzled); 1/sum kept in regs, applied after AV.
        float p32sav[4], invs[4];
#pragma unroll
        for (int i = 0; i < 4; ++i) {
          float p0 = __expf(S[0][i]);
          float p1 = __expf(S[1][i]);
          float p2 = (l15 == 0) ? __expf(S[2][i]) : 0.f;
          int prow = ea * 48 + mtl * 16 + g16 * 4 + i;
          ST16(sm, OFF_P + prow * 80 + swp(prow, l15 * 2), f2bfh(p0));
          ST16(sm, OFF_P + prow * 80 + swp(prow, 32 + l15 * 2), f2bfh(p1));
          float s = p0 + p1 + p2;
          s += __shfl_xor(s, 1, 64);
          s += __shfl_xor(s, 2, 64);
          s += __shfl_xor(s, 4, 64);
          s += __shfl_xor(s, 8, 64);
          invs[i] = 1.0f / s;
          p32sav[i] = __shfl(p2, lane & 48, 64);
        }
        asm volatile("s_waitcnt lgkmcnt(0)" ::: "memory");
        // ---- AV (K=32 MFMA) + key-32 rank-1; normalize; write attn ----
        {
          int parow = ea * 48 + mtl * 16 + l15;
          bf16x8 pa = LD8(sm, OFF_P + parow * 80 + swp(parow, g16 * 16));
#pragma unroll
          for (int nt = 0; nt < 4; ++nt) {
            int col = nt * 16 + l15;
            float v32v = bf2f(LD16(sm, OFF_V32 + (ea * 64 + col) * 2));
            bf16x8 vb = LD8(sm, OFF_VT + (ea * 64 + col) * 80 + g16 * 16);
            f32x4 acc = {0.f, 0.f, 0.f, 0.f};
            acc = MM(pa, vb, acc);
#pragma unroll
            for (int i = 0; i < 4; ++i) {
              float o = (acc[i] + p32sav[i] * v32v) * invs[i];
              int lr = mtl * 16 + g16 * 4 + i;
              if (lr < 33) {
                int qrow = e33 + lr;
                ST16(sm, OFF_Q + qrow * 144 + sw(qrow, col * 2), f2bfh(o));
              }
            }
          }
        }
        asm volatile("s_waitcnt lgkmcnt(0)" ::: "memory");
        // ---- Wu accumulate (K=64 slice of Wu at rows h*64..) ----
        {
          int arow = e33 + mtl * 16 + l15;
          bf16x8 a0 = LD8(sm, OFF_Q + arow * 144 + sw(arow, g16 * 16));
          bf16x8 a1 = LD8(sm, OFF_Q + arow * 144 + sw(arow, 64 + g16 * 16));
#pragma unroll
          for (int nt = 0; nt < 4; ++nt) {
            wu[nt] = MM(a0, WS[wu8 + (nt * 8 + h * 2) * 64 + lane], wu[nt]);
            wu[nt] =
                MM(a1, WS[wu8 + (nt * 8 + h * 2 + 1) * 64 + lane], wu[nt]);
          }
        }
      }
      __syncthreads();
    }  // heads

    // ---- LN1 in-register (wave's owned rows) ----
    if (att) {
#pragma unroll
      for (int i = 0; i < 4; ++i) {
        int lr = mtl * 16 + g16 * 4 + i;
        int grow = e33 + lr;
        bool ok = (lr < 33);
        float v[4];
#pragma unroll
        for (int nt = 0; nt < 4; ++nt) {
          int col = nt * 16 + l15;
          float xr =
              ok ? bf2f(LD16(sm, OFF_X + grow * 144 + sw(grow, col * 2)))
                 : 0.f;
          v[nt] = wu[nt][i] + xr;
        }
        float s = v[0] + v[1] + v[2] + v[3];
        s += __shfl_xor(s, 1, 64); s += __shfl_xor(s, 2, 64);
        s += __shfl_xor(s, 4, 64); s += __shfl_xor(s, 8, 64);
        float mu = s * 0.015625f;
        float q2 = 0.f;
#pragma unroll
        for (int nt = 0; nt < 4; ++nt) { float d = v[nt] - mu; q2 += d * d; }
        q2 += __shfl_xor(q2, 1, 64); q2 += __shfl_xor(q2, 2, 64);
        q2 += __shfl_xor(q2, 4, 64); q2 += __shfl_xor(q2, 8, 64);
        float inv = rsqrtf(q2 * 0.015625f + 1e-5f);
#pragma unroll
        for (int nt = 0; nt < 4; ++nt) {
          int col = nt * 16 + l15;
          float o = (v[nt] - mu) * inv * p.ln1_g[L * 64 + col] +
                    p.ln1_b[L * 64 + col];
          if (ok) ST16(sm, OFF_X + grow * 144 + sw(grow, col * 2), f2bfh(o));
        }
      }
    }
    __syncthreads();

    // ---- FF (5 M-tiles, one per wave wv<5; same-wave t1 produce/consume) ----
    f32x4 ff[4];
#pragma unroll
    for (int nt = 0; nt < 4; ++nt) {
      float bv = p.ff_b2[L * 64 + nt * 16 + l15];
      ff[nt] = {bv, bv, bv, bv};
    }
    const bool ffw = wv < 5;
    const int fmt = wv;
#pragma unroll
    for (int cc = 0; cc < 4; ++cc) {
      if (ffw) {
        int arow = fmt * 16 + l15;
        bf16x8 a0 = LD8(sm, OFF_X + arow * 144 + sw(arow, g16 * 16));
        bf16x8 a1 = LD8(sm, OFF_X + arow * 144 + sw(arow, 64 + g16 * 16));
#pragma unroll
        for (int nt = 0; nt < 4; ++nt) {
          float b1 = p.ff_b1[L * 256 + cc * 64 + nt * 16 + l15];
          f32x4 hh = {b1, b1, b1, b1};
          int f0 = (cc * 4 + nt) * 2;
          hh = MM(a0, WS[w18 + f0 * 64 + lane], hh);
          hh = MM(a1, WS[w18 + (f0 + 1) * 64 + lane], hh);
#pragma unroll
          for (int i = 0; i < 4; ++i) {
            int trow = fmt * 16 + g16 * 4 + i;
            ST16(sm, OFF_T1 + trow * 144 + sw(trow, (nt * 16 + l15) * 2),
                 f2bfh(fmaxf(hh[i], 0.f)));
          }
        }
        asm volatile("s_waitcnt lgkmcnt(0)" ::: "memory");
        bf16x8 ta = LD8(sm, OFF_T1 + arow * 144 + sw(arow, g16 * 16));
        bf16x8 tb = LD8(sm, OFF_T1 + arow * 144 + sw(arow, 64 + g16 * 16));
#pragma unroll
        for (int nt = 0; nt < 4; ++nt) {
          ff[nt] = MM(ta, WS[w28 + (nt * 8 + cc * 2) * 64 + lane], ff[nt]);
          ff[nt] = MM(tb, WS[w28 + (nt * 8 + cc * 2 + 1) * 64 + lane], ff[nt]);
        }
      }
    }
    // ---- LN2 in-register (wave's fmt rows) ----
    if (ffw) {
#pragma unroll
      for (int i = 0; i < 4; ++i) {
        int grow = fmt * 16 + g16 * 4 + i;
        bool ok = grow < 66;
        float v[4];
#pragma unroll
        for (int nt = 0; nt < 4; ++nt) {
          int col = nt * 16 + l15;
          float xr =
              ok ? bf2f(LD16(sm, OFF_X + grow * 144 + sw(grow, col * 2)))
                 : 0.f;
          v[nt] = ff[nt][i] + xr;
        }
        float s = v[0] + v[1] + v[2] + v[3];
        s += __shfl_xor(s, 1, 64); s += __shfl_xor(s, 2, 64);
        s += __shfl_xor(s, 4, 64); s += __shfl_xor(s, 8, 64);
        float mu = s * 0.015625f;
        float q2 = 0.f;
#pragma unroll
        for (int nt = 0; nt < 4; ++nt) { float d = v[nt] - mu; q2 += d * d; }
        q2 += __shfl_xor(q2, 1, 64); q2 += __shfl_xor(q2, 2, 64);
        q2 += __shfl_xor(q2, 4, 64); q2 += __shfl_xor(q2, 8, 64);
        float inv = rsqrtf(q2 * 0.015625f + 1e-5f);
#pragma unroll
        for (int nt = 0; nt < 4; ++nt) {
          int col = nt * 16 + l15;
          float o = (v[nt] - mu) * inv * p.ln2_g[L * 64 + col] +
                    p.ln2_b[L * 64 + col];
          if (ok) ST16(sm, OFF_X + grow * 144 + sw(grow, col * 2), f2bfh(o));
        }
      }
    }
    __syncthreads();
  }  // layers

  // ---- toprobs -> t1 (bf16): flat split over 20 (mt,nt) pairs ----
  for (int wid = wv; wid < 20; wid += 8) {
    int mt = wid >> 2, nt = wid & 3;
    int arow = mt * 16 + l15;
    bf16x8 a0 = LD8(sm, OFF_X + arow * 144 + sw(arow, g16 * 16));
    bf16x8 a1 = LD8(sm, OFF_X + arow * 144 + sw(arow, 64 + g16 * 16));
    int col = nt * 16 + l15;
    float tb = p.toprobs_b[col];
    f32x4 acc = {tb, tb, tb, tb};
    acc = MM(a0, WS[WS_TOP + (nt * 2) * 64 + lane], acc);
    acc = MM(a1, WS[WS_TOP + (nt * 2 + 1) * 64 + lane], acc);
#pragma unroll
    for (int i = 0; i < 4; ++i) {
      int r = mt * 16 + g16 * 4 + i;
      ST16(sm, OFF_T1 + r * 144 + sw(r, col * 2), f2bfh(acc[i]));
    }
  }
  __syncthreads();

  // ---- epilogue (VALU, fp32 weights direct; threads 0..255 active) ----
  {
    const bool act = tid < 256;
    const int gg = (tid >> 7) & 1;
    const int j = tid & 127;
    const size_t be = (size_t)(b0 + gg);
    if (act) {
      float s = p.cls_b1[j];
      const int row65 = gg * 33 + 32;
      const int t1off = OFF_T1 + row65 * 144;
      for (int k2 = 0; k2 < 64; k2 += 4) {
        uint2 w = *(const uint2*)(sm + t1off + sw(row65, k2 * 2));
        s += bf2f((short)w.x) * p.cls_W1[k2 * 128 + j];
        s += bf2f((short)(w.x >> 16)) * p.cls_W1[(k2 + 1) * 128 + j];
        s += bf2f((short)w.y) * p.cls_W1[(k2 + 2) * 128 + j];
        s += bf2f((short)(w.y >> 16)) * p.cls_W1[(k2 + 3) * 128 + j];
      }
      for (int k2 = 0; k2 < 32; k2 += 4) {
        float4 ph = *(const float4*)(sm + OFF_PHB + (gg * 32 + k2) * 4);
        s += ph.x * p.cls_W1[(64 + k2) * 128 + j];
        s += ph.y * p.cls_W1[(65 + k2) * 128 + j];
        s += ph.z * p.cls_W1[(66 + k2) * 128 + j];
        s += ph.w * p.cls_W1[(67 + k2) * 128 + j];
      }
      *(float*)(sm + OFF_ZZ1 + (gg * 128 + j) * 4) = fmaxf(s, 0.f);
    }
    __syncthreads();
    if (act && j < 64) {
      float s = p.cls_b2[j];
      for (int k2 = 0; k2 < 128; k2 += 4) {
        float4 z = *(const float4*)(sm + OFF_ZZ1 + (gg * 128 + k2) * 4);
        s += z.x * p.cls_W2[k2 * 64 + j];
        s += z.y * p.cls_W2[(k2 + 1) * 64 + j];
        s += z.z * p.cls_W2[(k2 + 2) * 64 + j];
        s += z.w * p.cls_W2[(k2 + 3) * 64 + j];
      }
      *(float*)(sm + OFF_ZZ2 + (gg * 64 + j) * 4) = fmaxf(s, 0.f);
    }
    __syncthreads();
    if (act && j < 8) {
      float s = p.cls_b3[j];
      for (int k2 = 0; k2 < 64; k2 += 4) {
        float4 z = *(const float4*)(sm + OFF_ZZ2 + (gg * 64 + k2) * 4);
        s += z.x * p.cls_W3[k2 * 8 + j];
        s += z.y * p.cls_W3[(k2 + 1) * 8 + j];
        s += z.z * p.cls_W3[(k2 + 2) * 8 + j];
        s += z.w * p.cls_W3[(k2 + 3) * 8 + j];
      }
      *(float*)(sm + OFF_PB + (gg * 8 + j) * 4) = s;
    }
    __syncthreads();
    if (act && j == 0) {
      float* pb = (float*)(sm + OFF_PB) + gg * 8;
      float m = pb[0];
#pragma unroll
      for (int k2 = 1; k2 < 8; ++k2) m = fmaxf(m, pb[k2]);
      float sum = 0.f, e8[8];
#pragma unroll
      for (int k2 = 0; k2 < 8; ++k2) {
        e8[k2] = __expf(pb[k2] - m);
        sum += e8[k2];
      }
      float inv = 1.f / sum;
#pragma unroll
      for (int k2 = 0; k2 < 8; ++k2) pb[k2] = e8[k2] * inv;
    }
    __syncthreads();
    if (act && j < 32) {
      float s = 0.f;
#pragma unroll
      for (int k2 = 0; k2 < 8; ++k2)
        s += *(float*)(sm + OFF_PB + (gg * 8 + k2) * 4) * p.p_e_w[k2 * 32 + j];
      *(float*)(sm + OFF_PR + (gg * 32 + j) * 4) = s;
      p.out[(size_t)BTOT * 90 + be * 32 + j] = s;
      p.out[(size_t)BTOT * 122 + be * 32 + j] = s;
    }
    __syncthreads();
    if (act) {
      if (j < 6) {
        float s = p.qself_b[j];
        const int row0 = gg * 33;
        const int t1off = OFF_T1 + row0 * 144;
        for (int k2 = 0; k2 < 64; k2 += 4) {
          uint2 w = *(const uint2*)(sm + t1off + sw(row0, k2 * 2));
          s += bf2f((short)w.x) * p.qself_W[k2 * 6 + j];
          s += bf2f((short)(w.x >> 16)) * p.qself_W[(k2 + 1) * 6 + j];
          s += bf2f((short)w.y) * p.qself_W[(k2 + 2) * 6 + j];
          s += bf2f((short)(w.y >> 16)) * p.qself_W[(k2 + 3) * 6 + j];
        }
        for (int k2 = 0; k2 < 32; k2 += 4) {
          float4 pr = *(const float4*)(sm + OFF_PR + (gg * 32 + k2) * 4);
          s += pr.x * p.qself_W[(64 + k2) * 6 + j];
          s += pr.y * p.qself_W[(65 + k2) * 6 + j];
          s += pr.z * p.qself_W[(66 + k2) * 6 + j];
          s += pr.w * p.qself_W[(67 + k2) * 6 + j];
        }
        p.out[be * 26 + j] = s;
      } else if (j >= 6 && j < 26) {
        int en = j - 6;
        float s = p.qint_b[0];
        const int rowe = gg * 33 + 1 + en;
        const int t1off = OFF_T1 + rowe * 144;
        for (int k2 = 0; k2 < 64; k2 += 4) {
          uint2 w = *(const uint2*)(sm + t1off + sw(rowe, k2 * 2));
          s += bf2f((short)w.x) * p.qint_W[k2];
          s += bf2f((short)(w.x >> 16)) * p.qint_W[k2 + 1];
          s += bf2f((short)w.y) * p.qint_W[k2 + 2];
          s += bf2f((short)(w.y >> 16)) * p.qint_W[k2 + 3];
        }
        for (int k2 = 0; k2 < 32; k2 += 4) {
          float4 pr = *(const float4*)(sm + OFF_PR + (gg * 32 + k2) * 4);
          s += pr.x * p.qint_W[64 + k2];
          s += pr.y * p.qint_W[65 + k2];
          s += pr.z * p.qint_W[66 + k2];
          s += pr.w * p.qint_W[67 + k2];
        }
        p.out[be * 26 + 6 + en] = s;
      } else if (j >= 32 && j < 96) {
        int c = j - 32;
        const int row65 = gg * 33 + 32;
        p.out[(size_t)BTOT * 26 + be * 64 + c] =
            bf2f(LD16(sm, OFF_T1 + row65 * 144 + sw(row65, c * 2)));
      }
    }
  }
}

// ---------------- fallback: round-1 fp32 kernel (proven) ----------------
#define TIN 32
#define TDIM 32
#define T 33
#define E 64
#define NH 4
#define NDEPTH 2

struct FParams {
  const float *inputs, *hidden, *p_h, *emb_W, *emb_b;
  const float *Wq, *Wk, *Wv, *Wu, *bu, *ln1_g, *ln1_b;
  const float *ff_W1, *ff_b1, *ff_W2, *ff_b2, *ln2_g, *ln2_b;
  const float *toprobs_W, *toprobs_b;
  const float *cls_W1, *cls_b1, *cls_W2, *cls_b2, *cls_W3, *cls_b3;
  const float *qself_W, *qself_b, *qint_W, *qint_b, *p_e_w;
  float* out;
};

__global__ __launch_bounds__(256) void fused_fb(FParams p) {
  const int b = blockIdx.x;
  const int tid = threadIdx.x;
  const int lane = tid & 63;
  const int wvv = tid >> 6;

  __shared__ float xb[T * E], t0[T * E], kT[E * T], vbuf[T * E], ab[T * E],
      scb[T * T];
  __shared__ float zz1[128], zz2[64], pbs[8], prs[32], phb[32];

  for (int idx = tid; idx < TIN * TDIM; idx += 256)
    scb[idx] = p.inputs[(size_t)b * TIN * TDIM + idx];
  if (tid < 32) phb[tid] = p.p_h[(size_t)b * 32 + tid];
  __syncthreads();
  {
    float s[8];
#pragma unroll
    for (int j = 0; j < 8; ++j) s[j] = 0.f;
    for (int k = 0; k < TDIM; ++k) {
      float w = p.emb_W[k * E + lane];
#pragma unroll
      for (int j = 0; j < 8; ++j) s[j] += scb[(wvv + 4 * j) * TDIM + k] * w;
    }
    float eb = p.emb_b[lane];
#pragma unroll
    for (int j = 0; j < 8; ++j) xb[(wvv + 4 * j) * E + lane] = s[j] + eb;
    if (wvv == 0) xb[32 * E + lane] = p.hidden[(size_t)b * E + lane];
  }
  __syncthreads();
  const float scale = SCL;
  for (int i = 0; i < NDEPTH; ++i) {
    {
      float bv = p.bu[i * E + lane];
#pragma unroll
      for (int j = 0; j < 9; ++j) {
        int r = wvv + 4 * j;
        if (j < 8 || wvv == 0) ab[r * E + lane] = bv;
      }
    }
    __syncthreads();
    for (int h = 0; h < NH; ++h) {
      const size_t qko = (size_t)i * E * 256 + h * E;
      {
        float sq[9], sk[9], sv[9];
#pragma unroll
        for (int j = 0; j < 9; ++j) { sq[j] = 0; sk[j] = 0; sv[j] = 0; }
        for (int k = 0; k < E; ++k) {
          float wq = p.Wq[qko + k * 256 + lane];
          float wk = p.Wk[qko + k * 256 + lane];
          float wvl = p.Wv[qko + k * 256 + lane];
#pragma unroll
          for (int j = 0; j < 9; ++j) {
            int r = wvv + 4 * j; if (r > 32) r = 32;
            float xv = xb[r * E + k];
            sq[j] += xv * wq; sk[j] += xv * wk; sv[j] += xv * wvl;
          }
        }
#pragma unroll
        for (int j = 0; j < 9; ++j) {
          int r = wvv + 4 * j;
          if (j < 8 || wvv == 0) {
            t0[r * E + lane] = sq[j] * scale;
            kT[lane * T + r] = sk[j] * scale;
            vbuf[r * E + lane] = sv[j];
          }
        }
      }
      __syncthreads();
      if (lane < T) {
        for (int qi = wvv; qi < T; qi += 4) {
          float s = 0.f;
          for (int e = 0; e < E; ++e) s += t0[qi * E + e] * kT[e * T + lane];
          scb[qi * T + lane] = s;
        }
      }
      __syncthreads();
      if (tid < T) {
        float m = -1e30f;
        for (int k2 = 0; k2 < T; ++k2) m = fmaxf(m, scb[tid * T + k2]);
        float sum = 0.f;
        for (int k2 = 0; k2 < T; ++k2) {
          float ev = __expf(scb[tid * T + k2] - m);
          scb[tid * T + k2] = ev; sum += ev;
        }
        float inv = 1.f / sum;
        for (int k2 = 0; k2 < T; ++k2) scb[tid * T + k2] *= inv;
      }
      __syncthreads();
      {
        float s[9];
#pragma unroll
        for (int j = 0; j < 9; ++j) s[j] = 0.f;
        for (int k2 = 0; k2 < T; ++k2) {
          float vload = vbuf[k2 * E + lane];
#pragma unroll
          for (int j = 0; j < 9; ++j) {
            int r = wvv + 4 * j; if (r > 32) r = 32;
            s[j] += scb[r * T + k2] * vload;
          }
        }
#pragma unroll
        for (int j = 0; j < 9; ++j) {
          int r = wvv + 4 * j;
          if (j < 8 || wvv == 0) t0[r * E + lane] = s[j];
        }
      }
      __syncthreads();
      {
        const size_t wuo = (size_t)i * 256 * 64 + (size_t)h * 64 * 64;
        float s[9];
#pragma unroll
        for (int j = 0; j < 9; ++j) s[j] = 0.f;
        for (int k2 = 0; k2 < E; ++k2) {
          float w = p.Wu[wuo + k2 * 64 + lane];
#pragma unroll
          for (int j = 0; j < 9; ++j) {
            int r = wvv + 4 * j; if (r > 32) r = 32;
            s[j] += t0[r * E + k2] * w;
          }
        }
#pragma unroll
        for (int j = 0; j < 9; ++j) {
          int r = wvv + 4 * j;
          if (j < 8 || wvv == 0) ab[r * E + lane] += s[j];
        }
      }
      __syncthreads();
    }
    {
      float gg = p.ln1_g[i * E + lane], bb = p.ln1_b[i * E + lane];
      for (int r = wvv; r < T; r += 4) {
        float v = ab[r * E + lane] + xb[r * E + lane];
        float s = v;
#pragma unroll
        for (int o = 32; o >= 1; o >>= 1) s += __shfl_xor(s, o, 64);
        float mu = s * (1.f / 64.f);
        float d = v - mu, q2 = d * d;
#pragma unroll
        for (int o = 32; o >= 1; o >>= 1) q2 += __shfl_xor(q2, o, 64);
        xb[r * E + lane] = d * (1.f / sqrtf(q2 * (1.f / 64.f) + 1e-5f)) * gg + bb;
      }
    }
    __syncthreads();
    {
      float bv = p.ff_b2[i * E + lane];
#pragma unroll
      for (int j = 0; j < 9; ++j) {
        int r = wvv + 4 * j;
        if (j < 8 || wvv == 0) ab[r * E + lane] = bv;
      }
    }
    __syncthreads();
    for (int cc = 0; cc < 4; ++cc) {
      {
        const size_t w1o = (size_t)i * E * 256 + cc * 64;
        float b1 = p.ff_b1[i * 256 + cc * 64 + lane];
        float s[9];
#pragma unroll
        for (int j = 0; j < 9; ++j) s[j] = b1;
        for (int k = 0; k < E; ++k) {
          float w = p.ff_W1[w1o + k * 256 + lane];
#pragma unroll
          for (int j = 0; j < 9; ++j) {
            int r = wvv + 4 * j; if (r > 32) r = 32;
            s[j] += xb[r * E + k] * w;
          }
        }
#pragma unroll
        for (int j = 0; j < 9; ++j) {
          int r = wvv + 4 * j;
          if (j < 8 || wvv == 0) t0[r * E + lane] = fmaxf(s[j], 0.f);
        }
      }
      __syncthreads();
      {
        const size_t w2o = (size_t)i * 256 * 64 + (size_t)cc * 64 * 64;
        float s[9];
#pragma unroll
        for (int j = 0; j < 9; ++j) s[j] = 0.f;
        for (int k = 0; k < E; ++k) {
          float w = p.ff_W2[w2o + k * 64 + lane];
#pragma unroll
          for (int j = 0; j < 9; ++j) {
            int r = wvv + 4 * j; if (r > 32) r = 32;
            s[j] += t0[r * E + k] * w;
          }
        }
#pragma unroll
        for (int j = 0; j < 9; ++j) {
          int r = wvv + 4 * j;
          if (j < 8 || wvv == 0) ab[r * E + lane] += s[j];
        }
      }
      __syncthreads();
    }
    {
      float gg = p.ln2_g[i * E + lane], bb = p.ln2_b[i * E + lane];
      for (int r = wvv; r < T; r += 4) {
        float v = ab[r * E + lane] + xb[r * E + lane];
        float s = v;
#pragma unroll
        for (int o = 32; o >= 1; o >>= 1) s += __shfl_xor(s, o, 64);
        float mu = s * (1.f / 64.f);
        float d = v - mu, q2 = d * d;
#pragma unroll
        for (int o = 32; o >= 1; o >>= 1) q2 += __shfl_xor(q2, o, 64);
        xb[r * E + lane] = d * (1.f / sqrtf(q2 * (1.f / 64.f) + 1e-5f)) * gg + bb;
      }
    }
    __syncthreads();
  }
  {
    float tb = p.toprobs_b[lane];
    float s[9];
#pragma unroll
    for (int j = 0; j < 9; ++j) s[j] = tb;
    for (int k = 0; k < E; ++k) {
      float w = p.toprobs_W[k * E + lane];
#pragma unroll
      for (int j = 0; j < 9; ++j) {
        int r = wvv + 4 * j; if (r > 32) r = 32;
        s[j] += xb[r * E + k] * w;
      }
    }
#pragma unroll
    for (int j = 0; j < 9; ++j) {
      int r = wvv + 4 * j;
      if (j < 8 || wvv == 0) t0[r * E + lane] = s[j];
    }
  }
  __syncthreads();
  if (tid < 128) {
    float s = p.cls_b1[tid];
    for (int k = 0; k < E; ++k) s += t0[32 * E + k] * p.cls_W1[k * 128 + tid];
    for (int k = 0; k < 32; ++k) s += phb[k] * p.cls_W1[(E + k) * 128 + tid];
    zz1[tid] = fmaxf(s, 0.f);
  }
  __syncthreads();
  if (tid < 64) {
    float s = p.cls_b2[tid];
    for (int k = 0; k < 128; ++k) s += zz1[k] * p.cls_W2[k * 64 + tid];
    zz2[tid] = fmaxf(s, 0.f);
  }
  __syncthreads();
  if (tid < 8) {
    float s = p.cls_b3[tid];
    for (int k = 0; k < 64; ++k) s += zz2[k] * p.cls_W3[k * 8 + tid];
    pbs[tid] = s;
  }
  __syncthreads();
  if (tid == 0) {
    float m = pbs[0];
#pragma unroll
    for (int k = 1; k < 8; ++k) m = fmaxf(m, pbs[k]);
    float e8[8], sum = 0.f;
#pragma unroll
    for (int k = 0; k < 8; ++k) { e8[k] = __expf(pbs[k] - m); sum += e8[k]; }
    float inv = 1.f / sum;
#pragma unroll
    for (int k = 0; k < 8; ++k) pbs[k] = e8[k] * inv;
  }
  __syncthreads();
  if (tid < 32) {
    float s = 0.f;
#pragma unroll
    for (int k = 0; k < 8; ++k) s += pbs[k] * p.p_e_w[k * 32 + tid];
    prs[tid] = s;
    p.out[(size_t)BTOT * 90 + (size_t)b * 32 + tid] = s;
    p.out[(size_t)BTOT * 122 + (size_t)b * 32 + tid] = s;
  }
  __syncthreads();
  if (tid < 6) {
    float s = p.qself_b[tid];
    for (int k = 0; k < E; ++k) s += t0[k] * p.qself_W[k * 6 + tid];
    for (int k = 0; k < 32; ++k) s += prs[k] * p.qself_W[(E + k) * 6 + tid];
    p.out[(size_t)b * 26 + tid] = s;
  }
  if (tid >= 64 && tid < 84) {
    int en = tid - 64;
    float s = p.qint_b[0];
    for (int k = 0; k < E; ++k) s += t0[(1 + en) * E + k] * p.qint_W[k];
    for (int k = 0; k < 32; ++k) s += prs[k] * p.qint_W[E + k];
    p.out[(size_t)b * 26 + 6 + en] = s;
  }
  if (tid >= 128 && tid < 192) {
    int c2 = tid - 128;
    p.out[(size_t)BTOT * 26 + (size_t)b * 64 + c2] = t0[32 * E + c2];
  }
}

extern "C" void kernel_launch(void* const* d_in, const int* in_sizes, int n_in,
                              void* d_out, int out_size, void* d_ws,
                              size_t ws_size, hipStream_t stream) {
  (void)in_sizes; (void)n_in; (void)out_size;
  if (ws_size >= (size_t)WS_BYTES) {
    PP pp;
    pp.emb = (const float*)d_in[3];
    pp.wq = (const float*)d_in[5];
    pp.wk = (const float*)d_in[6];
    pp.wvp = (const float*)d_in[7];
    pp.wu = (const float*)d_in[8];
    pp.w1 = (const float*)d_in[12];
    pp.w2 = (const float*)d_in[14];
    pp.top = (const float*)d_in[18];
    pp.dst = (short*)d_ws;
    hipLaunchKernelGGL(prep_frags, dim3(128), dim3(256), 0, stream, pp);

    MP p;
    p.inputs = (const float*)d_in[0];
    p.hidden = (const float*)d_in[1];
    p.p_h = (const float*)d_in[2];
    p.emb_b = (const float*)d_in[4];
    p.bu = (const float*)d_in[9];
    p.ln1_g = (const float*)d_in[10];
    p.ln1_b = (const float*)d_in[11];
    p.ff_b1 = (const float*)d_in[13];
    p.ff_b2 = (const float*)d_in[15];
    p.ln2_g = (const float*)d_in[16];
    p.ln2_b = (const float*)d_in[17];
    p.toprobs_b = (const float*)d_in[19];
    p.cls_W1 = (const float*)d_in[20];
    p.cls_b1 = (const float*)d_in[21];
    p.cls_W2 = (const float*)d_in[22];
    p.cls_b2 = (const float*)d_in[23];
    p.cls_W3 = (const float*)d_in[24];
    p.cls_b3 = (const float*)d_in[25];
    p.qself_W = (const float*)d_in[26];
    p.qself_b = (const float*)d_in[27];
    p.qint_W = (const float*)d_in[28];
    p.qint_b = (const float*)d_in[29];
    p.p_e_w = (const float*)d_in[30];
    p.ws = (const bf16x8*)d_ws;
    p.out = (float*)d_out;
    hipLaunchKernelGGL(fused_mfma, dim3(BTOT / 2), dim3(512), 0, stream, p);
  } else {
    FParams p;
    p.inputs = (const float*)d_in[0];
    p.hidden = (const float*)d_in[1];
    p.p_h = (const float*)d_in[2];
    p.emb_W = (const float*)d_in[3];
    p.emb_b = (const float*)d_in[4];
    p.Wq = (const float*)d_in[5];
    p.Wk = (const float*)d_in[6];
    p.Wv = (const float*)d_in[7];
    p.Wu = (const float*)d_in[8];
    p.bu = (const float*)d_in[9];
    p.ln1_g = (const float*)d_in[10];
    p.ln1_b = (const float*)d_in[11];
    p.ff_W1 = (const float*)d_in[12];
    p.ff_b1 = (const float*)d_in[13];
    p.ff_W2 = (const float*)d_in[14];
    p.ff_b2 = (const float*)d_in[15];
    p.ln2_g = (const float*)d_in[16];
    p.ln2_b = (const float*)d_in[17];
    p.toprobs_W = (const float*)d_in[18];
    p.toprobs_b = (const float*)d_in[19];
    p.cls_W1 = (const float*)d_in[20];
    p.cls_b1 = (const float*)d_in[21];
    p.cls_W2 = (const float*)d_in[22];
    p.cls_b2 = (const float*)d_in[23];
    p.cls_W3 = (const float*)d_in[24];
    p.cls_b3 = (const float*)d_in[25];
    p.qself_W = (const float*)d_in[26];
    p.qself_b = (const float*)d_in[27];
    p.qint_W = (const float*)d_in[28];
    p.qint_b = (const float*)d_in[29];
    p.p_e_w = (const float*)d_in[30];
    p.out = (float*)d_out;
    hipLaunchKernelGGL(fused_fb, dim3(BTOT), dim3(256), 0, stream, p);
  }
}

// Round 11
// 487.085 us; speedup vs baseline: 2.3538x; 2.3538x over previous
//
#include <hip/hip_runtime.h>
#include <hip/hip_bf16.h>
#include <stdint.h>

// PhaseUPDeT fused forward — round 13: REVERT to proven 488 µs anchor.
// Round-12 post-mortem: XOR swizzle (a) spilled (WRITE 6->398MB) — the
// per-access XOR address math added live temps at a zero-headroom register
// file; (b) conflicts ROSE 2.20e7->2.47e7 — the quarter-wave stride-144
// bank model was wrong. Lever closed on both axes.
// Session ledger: 575.8 -> 488.4 µs via 8-wave restructure, HW bf16 converts,
// no-max softmax + deferred normalization, SCL fold, packed stores, vectorized
// epilogue. Register file exactly full (64 VGPR + ~64 AGPR = 128 cap); all
// expansion levers (hoist/6-wave/swizzle) proven to spill. This file is the
// verified best kernel.

typedef __hip_bfloat16 bf16;
using bf16x8 = __attribute__((ext_vector_type(8))) short;
using f32x4  = __attribute__((ext_vector_type(4))) float;
using s16x4  = __attribute__((ext_vector_type(4))) short;

#define BTOT 8192
#define SCL 0.35355339059327373f

// hand-rolled RNE (prep kernel only; runs once, perf-irrelevant)
__device__ __forceinline__ short f2bf(float f) {
  uint32_t u = __float_as_uint(f);
  return (short)((u + 0x7FFFu + ((u >> 16) & 1u)) >> 16);
}
__device__ __forceinline__ float bf2f(short s) {
  return __uint_as_float(((uint32_t)(uint16_t)s) << 16);
}
// f32 -> bf16 via official API: RNE, lowered by clang to the HW convert.
__device__ __forceinline__ short f2bfh(float f) {
  __hip_bfloat16 h = __float2bfloat16(f);
  return *reinterpret_cast<short*>(&h);
}
__device__ __forceinline__ f32x4 MM(bf16x8 a, bf16x8 b, f32x4 c) {
  return __builtin_amdgcn_mfma_f32_16x16x32_bf16(a, b, c, 0, 0, 0);
}

// ---------------- LDS layout (bytes) ----------------
#define OFF_X   0
#define OFF_Q   11520
#define OFF_K   23184
#define OFF_VT  34848
#define OFF_V32 45088
#define OFF_P   45344
#define OFF_T1  34848
#define OFF_ZZ1 46368
#define OFF_ZZ2 47392
#define OFF_PB  47904
#define OFF_PR  47968
#define OFF_PHB 53024
#define SMEM_SZ 53280

// ws fragment-slot offsets (units of bf16x8 = 8 elems)
#define WS_EMB 0
#define WS_WQ  256
#define WS_WK  4352
#define WS_WV  8448
#define WS_WU  12544
#define WS_W1  16640
#define WS_W2  20736
#define WS_TOP 24832
#define WS_BYTES 405504

__device__ __forceinline__ bf16x8 LD8(const uint8_t* sm, int off) {
  return *(const bf16x8*)(sm + off);
}
__device__ __forceinline__ void ST16(uint8_t* sm, int off, short v) {
  *(short*)(sm + off) = v;
}
__device__ __forceinline__ short LD16(const uint8_t* sm, int off) {
  return *(const short*)(sm + off);
}

// ---------------- prep kernel ----------------
struct PP {
  const float *emb, *wq, *wk, *wvp, *wu, *w1, *w2, *top;
  short* dst;
};

__global__ __launch_bounds__(256) void prep_frags(PP pp) {
  constexpr int START[15] = {0, 2048, 18432, 34816, 51200, 67584, 83968,
                             100352, 116736, 133120, 149504, 165888, 182272,
                             198656, 202752};
  for (int idx = blockIdx.x * 256 + threadIdx.x; idx < 202752;
       idx += gridDim.x * 256) {
#pragma unroll
    for (int t = 0; t < 14; ++t) {
      if (idx >= START[t] && idx < START[t + 1]) {
        int K, N; const float* s; float sc = 1.0f;
        switch (t) {
          case 0:  s = pp.emb;          K = 32;  N = 64;  break;
          case 1:  s = pp.wq;           K = 64;  N = 256; sc = SCL; break;
          case 2:  s = pp.wq + 16384;   K = 64;  N = 256; sc = SCL; break;
          case 3:  s = pp.wk;           K = 64;  N = 256; sc = SCL; break;
          case 4:  s = pp.wk + 16384;   K = 64;  N = 256; sc = SCL; break;
          case 5:  s = pp.wvp;          K = 64;  N = 256; break;
          case 6:  s = pp.wvp + 16384;  K = 64;  N = 256; break;
          case 7:  s = pp.wu;           K = 256; N = 64;  break;
          case 8:  s = pp.wu + 16384;   K = 256; N = 64;  break;
          case 9:  s = pp.w1;           K = 64;  N = 256; break;
          case 10: s = pp.w1 + 16384;   K = 64;  N = 256; break;
          case 11: s = pp.w2;           K = 256; N = 64;  break;
          case 12: s = pp.w2 + 16384;   K = 256; N = 64;  break;
          default: s = pp.top;          K = 64;  N = 64;  break;
        }
        int rel = idx - START[t];
        int lane = (rel >> 3) & 63, jj = rel & 7, fi = rel >> 9;
        int KS = K >> 5;
        int nt = fi / KS, ks = fi - nt * KS;
        int k = ks * 32 + ((lane >> 4) << 3) + jj;
        int n = nt * 16 + (lane & 15);
        pp.dst[idx] = f2bf(s[(size_t)k * N + n] * sc);
      }
    }
  }
}

// ---------------- main kernel ----------------
struct MP {
  const float *inputs, *hidden, *p_h;
  const float *emb_b, *bu, *ln1_g, *ln1_b, *ff_b1, *ff_b2, *ln2_g, *ln2_b,
      *toprobs_b;
  const float *cls_W1, *cls_b1, *cls_W2, *cls_b2, *cls_W3, *cls_b3;
  const float *qself_W, *qself_b, *qint_W, *qint_b, *p_e_w;
  const bf16x8* ws;
  float* out;
};

__global__ __launch_bounds__(512, 4) void fused_mfma(MP p) {
  __shared__ __align__(16) uint8_t sm[SMEM_SZ];
  const int tid = threadIdx.x;
  const int lane = tid & 63;
  const int wv = tid >> 6;  // 0..7
  const int g16 = lane >> 4;
  const int l15 = lane & 15;
  const int b0 = blockIdx.x * 2;
  const bf16x8* WS = p.ws;

  // ---- stage p_h, inputs (bf16, stride 40 @ OFF_T1), hidden ----
  if (tid < 64) {
    *(float*)(sm + OFF_PHB + tid * 4) =
        p.p_h[(size_t)(b0 + (tid >> 5)) * 32 + (tid & 31)];
  }
  for (int idx = tid; idx < 2048; idx += 512) {
    int r = idx >> 5, c = idx & 31;
    ST16(sm, OFF_T1 + r * 80 + c * 2, f2bfh(p.inputs[(size_t)b0 * 1024 + idx]));
  }
  if (tid < 128) {
    int e = tid >> 6, c = tid & 63;
    ST16(sm, OFF_X + (e * 33 + 32) * 144 + c * 2,
         f2bfh(p.hidden[(size_t)(b0 + e) * 64 + c]));
  }
  __syncthreads();

  // ---- emb GEMM: 16 (mt,nt) units over 8 waves ----
  {
#pragma unroll
    for (int uu = 0; uu < 2; ++uu) {
      int u = wv * 2 + uu;
      int mt = u >> 2, nt = u & 3;
      int arow = mt * 16 + l15;
      bf16x8 a = LD8(sm, OFF_T1 + arow * 80 + g16 * 16);
      int col = nt * 16 + l15;
      float eb = p.emb_b[col];
      f32x4 acc = {eb, eb, eb, eb};
      acc = MM(a, WS[WS_EMB + nt * 64 + lane], acc);
#pragma unroll
      for (int i = 0; i < 4; ++i) {
        int r = mt * 16 + g16 * 4 + i;
        int grow = (r >> 5) * 33 + (r & 31);
        ST16(sm, OFF_X + grow * 144 + col * 2, f2bfh(acc[i]));
      }
    }
  }
  __syncthreads();

  // attention-core ownership: wave wv<6 owns (elem ea, M-tile mtl)
  const bool att = wv < 6;
  const int ea = wv & 1;
  const int mtl = wv >> 1;  // 0..2 when att
  const int e33 = ea * 33;

  for (int L = 0; L < 2; ++L) {
    const int wq8 = WS_WQ + L * 2048, wk8 = WS_WK + L * 2048,
              wv8 = WS_WV + L * 2048, wu8 = WS_WU + L * 2048,
              w18 = WS_W1 + L * 2048, w28 = WS_W2 + L * 2048;

    // Wu accumulators (persist across heads), init with bu
    f32x4 wu[4];
#pragma unroll
    for (int nt = 0; nt < 4; ++nt) {
      float bv = p.bu[L * 64 + nt * 16 + l15];
      wu[nt] = {bv, bv, bv, bv};
    }

    for (int h = 0; h < 4; ++h) {
      // ---- QKV for head h: flat split over 20 (mt,nt) pairs, 8 waves ----
      // SCL pre-folded into prep'd Wq/Wk fragments.
      for (int wid = wv; wid < 20; wid += 8) {
        int mt = wid >> 2, nt = wid & 3;
        int arow = mt * 16 + l15;
        bf16x8 a0 = LD8(sm, OFF_X + arow * 144 + g16 * 16);
        bf16x8 a1 = LD8(sm, OFF_X + arow * 144 + 64 + g16 * 16);
        int col = nt * 16 + l15;
        int rb = mt * 16 + g16 * 4;
        int f0 = (h * 4 + nt) * 2;
        f32x4 q = {0.f, 0.f, 0.f, 0.f}, k = q, v = q;
        q = MM(a0, WS[wq8 + f0 * 64 + lane], q);
        q = MM(a1, WS[wq8 + (f0 + 1) * 64 + lane], q);
        k = MM(a0, WS[wk8 + f0 * 64 + lane], k);
        k = MM(a1, WS[wk8 + (f0 + 1) * 64 + lane], k);
        v = MM(a0, WS[wv8 + f0 * 64 + lane], v);
        v = MM(a1, WS[wv8 + (f0 + 1) * 64 + lane], v);
#pragma unroll
        for (int i = 0; i < 4; ++i) {
          int r = rb + i;
          if (r < 66) {
            ST16(sm, OFF_Q + r * 144 + col * 2, f2bfh(q[i]));
            ST16(sm, OFF_K + r * 144 + col * 2, f2bfh(k[i]));
          }
        }
        // v transposed: VT[(e*64+col)][tok]; packed b64 on the aligned path
        if (rb <= 28) {  // e=0, toks rb..rb+3, 8B-aligned
          s16x4 pv = {f2bfh(v[0]), f2bfh(v[1]), f2bfh(v[2]), f2bfh(v[3])};
          *(s16x4*)(sm + OFF_VT + col * 80 + rb * 2) = pv;
        } else if (rb >= 36 && rb <= 60) {  // e=1, toks rb-33.. (2B-aligned)
          int vb = OFF_VT + (64 + col) * 80 + (rb - 33) * 2;
          ST16(sm, vb, f2bfh(v[0]));
          ST16(sm, vb + 2, f2bfh(v[1]));
          ST16(sm, vb + 4, f2bfh(v[2]));
          ST16(sm, vb + 6, f2bfh(v[3]));
        } else if (rb == 32) {  // r=32: e0 tok32 -> V32; r=33..35: e1 tok0..2
          ST16(sm, OFF_V32 + col * 2, f2bfh(v[0]));
          int vb = OFF_VT + (64 + col) * 80;
          ST16(sm, vb, f2bfh(v[1]));
          ST16(sm, vb + 2, f2bfh(v[2]));
          ST16(sm, vb + 4, f2bfh(v[3]));
        } else if (rb == 64) {  // r=64: e1 tok31; r=65: e1 tok32 -> V32
          ST16(sm, OFF_VT + (64 + col) * 80 + 31 * 2, f2bfh(v[0]));
          ST16(sm, OFF_V32 + (64 + col) * 2, f2bfh(v[1]));
        }
      }
      __syncthreads();

      if (att) {
        // ---- scores: one (ea, mtl) tile per wave ----
        f32x4 S[3];
        {
          int arow = e33 + mtl * 16 + l15;
          bf16x8 a0 = LD8(sm, OFF_Q + arow * 144 + g16 * 16);
          bf16x8 a1 = LD8(sm, OFF_Q + arow * 144 + 64 + g16 * 16);
#pragma unroll
          for (int nt = 0; nt < 3; ++nt) {
            int brow = e33 + nt * 16 + l15;
            bf16x8 kb0 = LD8(sm, OFF_K + brow * 144 + g16 * 16);
            bf16x8 kb1 = LD8(sm, OFF_K + brow * 144 + 64 + g16 * 16);
            f32x4 acc = {0.f, 0.f, 0.f, 0.f};
            acc = MM(a0, kb0, acc);
            acc = MM(a1, kb1, acc);
            S[nt] = acc;
          }
        }
        // ---- softmax, no-max variant (scores O(1); shift-invariant) ----
        // Store RAW exp to P; keep 1/sum in registers, applied after AV.
        float p32sav[4], invs[4];
#pragma unroll
        for (int i = 0; i < 4; ++i) {
          float p0 = __expf(S[0][i]);
          float p1 = __expf(S[1][i]);
          float p2 = (l15 == 0) ? __expf(S[2][i]) : 0.f;
          // stores depend only on exp — issue before the sum reduction
          int prow = ea * 48 + mtl * 16 + g16 * 4 + i;
          ST16(sm, OFF_P + prow * 80 + l15 * 2, f2bfh(p0));
          ST16(sm, OFF_P + prow * 80 + (16 + l15) * 2, f2bfh(p1));
          float s = p0 + p1 + p2;
          s += __shfl_xor(s, 1, 64);
          s += __shfl_xor(s, 2, 64);
          s += __shfl_xor(s, 4, 64);
          s += __shfl_xor(s, 8, 64);
          invs[i] = 1.0f / s;
          p32sav[i] = __shfl(p2, lane & 48, 64);
        }
        asm volatile("s_waitcnt lgkmcnt(0)" ::: "memory");
        // ---- AV (K=32 MFMA) + key-32 rank-1; normalize; write attn ----
        {
          bf16x8 pa =
              LD8(sm, OFF_P + (ea * 48 + mtl * 16 + l15) * 80 + g16 * 16);
#pragma unroll
          for (int nt = 0; nt < 4; ++nt) {
            int col = nt * 16 + l15;
            float v32v = bf2f(LD16(sm, OFF_V32 + (ea * 64 + col) * 2));
            bf16x8 vb = LD8(sm, OFF_VT + (ea * 64 + col) * 80 + g16 * 16);
            f32x4 acc = {0.f, 0.f, 0.f, 0.f};
            acc = MM(pa, vb, acc);
#pragma unroll
            for (int i = 0; i < 4; ++i) {
              float o = (acc[i] + p32sav[i] * v32v) * invs[i];
              int lr = mtl * 16 + g16 * 4 + i;
              if (lr < 33)
                ST16(sm, OFF_Q + (e33 + lr) * 144 + col * 2, f2bfh(o));
            }
          }
        }
        asm volatile("s_waitcnt lgkmcnt(0)" ::: "memory");
        // ---- Wu accumulate (K=64 slice of Wu at rows h*64..) ----
        {
          int arow = e33 + mtl * 16 + l15;
          bf16x8 a0 = LD8(sm, OFF_Q + arow * 144 + g16 * 16);
          bf16x8 a1 = LD8(sm, OFF_Q + arow * 144 + 64 + g16 * 16);
#pragma unroll
          for (int nt = 0; nt < 4; ++nt) {
            wu[nt] = MM(a0, WS[wu8 + (nt * 8 + h * 2) * 64 + lane], wu[nt]);
            wu[nt] =
                MM(a1, WS[wu8 + (nt * 8 + h * 2 + 1) * 64 + lane], wu[nt]);
          }
        }
      }
      __syncthreads();
    }  // heads

    // ---- LN1 in-register (wave's owned rows) ----
    if (att) {
#pragma unroll
      for (int i = 0; i < 4; ++i) {
        int lr = mtl * 16 + g16 * 4 + i;
        int grow = e33 + lr;
        bool ok = (lr < 33);
        float v[4];
#pragma unroll
        for (int nt = 0; nt < 4; ++nt) {
          int col = nt * 16 + l15;
          float xr = ok ? bf2f(LD16(sm, OFF_X + grow * 144 + col * 2)) : 0.f;
          v[nt] = wu[nt][i] + xr;
        }
        float s = v[0] + v[1] + v[2] + v[3];
        s += __shfl_xor(s, 1, 64); s += __shfl_xor(s, 2, 64);
        s += __shfl_xor(s, 4, 64); s += __shfl_xor(s, 8, 64);
        float mu = s * 0.015625f;
        float q2 = 0.f;
#pragma unroll
        for (int nt = 0; nt < 4; ++nt) { float d = v[nt] - mu; q2 += d * d; }
        q2 += __shfl_xor(q2, 1, 64); q2 += __shfl_xor(q2, 2, 64);
        q2 += __shfl_xor(q2, 4, 64); q2 += __shfl_xor(q2, 8, 64);
        float inv = rsqrtf(q2 * 0.015625f + 1e-5f);
#pragma unroll
        for (int nt = 0; nt < 4; ++nt) {
          int col = nt * 16 + l15;
          float o = (v[nt] - mu) * inv * p.ln1_g[L * 64 + col] +
                    p.ln1_b[L * 64 + col];
          if (ok) ST16(sm, OFF_X + grow * 144 + col * 2, f2bfh(o));
        }
      }
    }
    __syncthreads();

    // ---- FF (5 M-tiles, one per wave wv<5; same-wave t1 produce/consume) ----
    f32x4 ff[4];
#pragma unroll
    for (int nt = 0; nt < 4; ++nt) {
      float bv = p.ff_b2[L * 64 + nt * 16 + l15];
      ff[nt] = {bv, bv, bv, bv};
    }
    const bool ffw = wv < 5;
    const int fmt = wv;
#pragma unroll
    for (int cc = 0; cc < 4; ++cc) {
      if (ffw) {
        int arow = fmt * 16 + l15;
        bf16x8 a0 = LD8(sm, OFF_X + arow * 144 + g16 * 16);
        bf16x8 a1 = LD8(sm, OFF_X + arow * 144 + 64 + g16 * 16);
#pragma unroll
        for (int nt = 0; nt < 4; ++nt) {
          float b1 = p.ff_b1[L * 256 + cc * 64 + nt * 16 + l15];
          f32x4 hh = {b1, b1, b1, b1};
          int f0 = (cc * 4 + nt) * 2;
          hh = MM(a0, WS[w18 + f0 * 64 + lane], hh);
          hh = MM(a1, WS[w18 + (f0 + 1) * 64 + lane], hh);
#pragma unroll
          for (int i = 0; i < 4; ++i)
            ST16(sm,
                 OFF_T1 + (fmt * 16 + g16 * 4 + i) * 144 + (nt * 16 + l15) * 2,
                 f2bfh(fmaxf(hh[i], 0.f)));
        }
        asm volatile("s_waitcnt lgkmcnt(0)" ::: "memory");
        bf16x8 ta = LD8(sm, OFF_T1 + arow * 144 + g16 * 16);
        bf16x8 tb = LD8(sm, OFF_T1 + arow * 144 + 64 + g16 * 16);
#pragma unroll
        for (int nt = 0; nt < 4; ++nt) {
          ff[nt] = MM(ta, WS[w28 + (nt * 8 + cc * 2) * 64 + lane], ff[nt]);
          ff[nt] = MM(tb, WS[w28 + (nt * 8 + cc * 2 + 1) * 64 + lane], ff[nt]);
        }
      }
    }
    // ---- LN2 in-register (wave's fmt rows) ----
    if (ffw) {
#pragma unroll
      for (int i = 0; i < 4; ++i) {
        int grow = fmt * 16 + g16 * 4 + i;
        bool ok = grow < 66;
        float v[4];
#pragma unroll
        for (int nt = 0; nt < 4; ++nt) {
          int col = nt * 16 + l15;
          float xr = ok ? bf2f(LD16(sm, OFF_X + grow * 144 + col * 2)) : 0.f;
          v[nt] = ff[nt][i] + xr;
        }
        float s = v[0] + v[1] + v[2] + v[3];
        s += __shfl_xor(s, 1, 64); s += __shfl_xor(s, 2, 64);
        s += __shfl_xor(s, 4, 64); s += __shfl_xor(s, 8, 64);
        float mu = s * 0.015625f;
        float q2 = 0.f;
#pragma unroll
        for (int nt = 0; nt < 4; ++nt) { float d = v[nt] - mu; q2 += d * d; }
        q2 += __shfl_xor(q2, 1, 64); q2 += __shfl_xor(q2, 2, 64);
        q2 += __shfl_xor(q2, 4, 64); q2 += __shfl_xor(q2, 8, 64);
        float inv = rsqrtf(q2 * 0.015625f + 1e-5f);
#pragma unroll
        for (int nt = 0; nt < 4; ++nt) {
          int col = nt * 16 + l15;
          float o = (v[nt] - mu) * inv * p.ln2_g[L * 64 + col] +
                    p.ln2_b[L * 64 + col];
          if (ok) ST16(sm, OFF_X + grow * 144 + col * 2, f2bfh(o));
        }
      }
    }
    __syncthreads();
  }  // layers

  // ---- toprobs -> t1 (bf16): flat split over 20 (mt,nt) pairs ----
  for (int wid = wv; wid < 20; wid += 8) {
    int mt = wid >> 2, nt = wid & 3;
    int arow = mt * 16 + l15;
    bf16x8 a0 = LD8(sm, OFF_X + arow * 144 + g16 * 16);
    bf16x8 a1 = LD8(sm, OFF_X + arow * 144 + 64 + g16 * 16);
    int col = nt * 16 + l15;
    float tb = p.toprobs_b[col];
    f32x4 acc = {tb, tb, tb, tb};
    acc = MM(a0, WS[WS_TOP + (nt * 2) * 64 + lane], acc);
    acc = MM(a1, WS[WS_TOP + (nt * 2 + 1) * 64 + lane], acc);
#pragma unroll
    for (int i = 0; i < 4; ++i) {
      int r = mt * 16 + g16 * 4 + i;
      ST16(sm, OFF_T1 + r * 144 + col * 2, f2bfh(acc[i]));
    }
  }
  __syncthreads();

  // ---- epilogue (VALU, fp32 weights direct; threads 0..255 active) ----
  {
    const bool act = tid < 256;
    const int gg = (tid >> 7) & 1;
    const int j = tid & 127;
    const size_t be = (size_t)(b0 + gg);
    if (act) {
      float s = p.cls_b1[j];
      const int t1off = OFF_T1 + (gg * 33 + 32) * 144;
      for (int k2 = 0; k2 < 64; k2 += 4) {
        uint2 w = *(const uint2*)(sm + t1off + k2 * 2);
        s += bf2f((short)w.x) * p.cls_W1[k2 * 128 + j];
        s += bf2f((short)(w.x >> 16)) * p.cls_W1[(k2 + 1) * 128 + j];
        s += bf2f((short)w.y) * p.cls_W1[(k2 + 2) * 128 + j];
        s += bf2f((short)(w.y >> 16)) * p.cls_W1[(k2 + 3) * 128 + j];
      }
      for (int k2 = 0; k2 < 32; k2 += 4) {
        float4 ph = *(const float4*)(sm + OFF_PHB + (gg * 32 + k2) * 4);
        s += ph.x * p.cls_W1[(64 + k2) * 128 + j];
        s += ph.y * p.cls_W1[(65 + k2) * 128 + j];
        s += ph.z * p.cls_W1[(66 + k2) * 128 + j];
        s += ph.w * p.cls_W1[(67 + k2) * 128 + j];
      }
      *(float*)(sm + OFF_ZZ1 + (gg * 128 + j) * 4) = fmaxf(s, 0.f);
    }
    __syncthreads();
    if (act && j < 64) {
      float s = p.cls_b2[j];
      for (int k2 = 0; k2 < 128; k2 += 4) {
        float4 z = *(const float4*)(sm + OFF_ZZ1 + (gg * 128 + k2) * 4);
        s += z.x * p.cls_W2[k2 * 64 + j];
        s += z.y * p.cls_W2[(k2 + 1) * 64 + j];
        s += z.z * p.cls_W2[(k2 + 2) * 64 + j];
        s += z.w * p.cls_W2[(k2 + 3) * 64 + j];
      }
      *(float*)(sm + OFF_ZZ2 + (gg * 64 + j) * 4) = fmaxf(s, 0.f);
    }
    __syncthreads();
    if (act && j < 8) {
      float s = p.cls_b3[j];
      for (int k2 = 0; k2 < 64; k2 += 4) {
        float4 z = *(const float4*)(sm + OFF_ZZ2 + (gg * 64 + k2) * 4);
        s += z.x * p.cls_W3[k2 * 8 + j];
        s += z.y * p.cls_W3[(k2 + 1) * 8 + j];
        s += z.z * p.cls_W3[(k2 + 2) * 8 + j];
        s += z.w * p.cls_W3[(k2 + 3) * 8 + j];
      }
      *(float*)(sm + OFF_PB + (gg * 8 + j) * 4) = s;
    }
    __syncthreads();
    if (act && j == 0) {
      float* pb = (float*)(sm + OFF_PB) + gg * 8;
      float m = pb[0];
#pragma unroll
      for (int k2 = 1; k2 < 8; ++k2) m = fmaxf(m, pb[k2]);
      float sum = 0.f, e8[8];
#pragma unroll
      for (int k2 = 0; k2 < 8; ++k2) {
        e8[k2] = __expf(pb[k2] - m);
        sum += e8[k2];
      }
      float inv = 1.f / sum;
#pragma unroll
      for (int k2 = 0; k2 < 8; ++k2) pb[k2] = e8[k2] * inv;
    }
    __syncthreads();
    if (act && j < 32) {
      float s = 0.f;
#pragma unroll
      for (int k2 = 0; k2 < 8; ++k2)
        s += *(float*)(sm + OFF_PB + (gg * 8 + k2) * 4) * p.p_e_w[k2 * 32 + j];
      *(float*)(sm + OFF_PR + (gg * 32 + j) * 4) = s;
      p.out[(size_t)BTOT * 90 + be * 32 + j] = s;
      p.out[(size_t)BTOT * 122 + be * 32 + j] = s;
    }
    __syncthreads();
    if (act) {
      if (j < 6) {
        float s = p.qself_b[j];
        const int t1off = OFF_T1 + (gg * 33) * 144;
        for (int k2 = 0; k2 < 64; k2 += 4) {
          uint2 w = *(const uint2*)(sm + t1off + k2 * 2);
          s += bf2f((short)w.x) * p.qself_W[k2 * 6 + j];
          s += bf2f((short)(w.x >> 16)) * p.qself_W[(k2 + 1) * 6 + j];
          s += bf2f((short)w.y) * p.qself_W[(k2 + 2) * 6 + j];
          s += bf2f((short)(w.y >> 16)) * p.qself_W[(k2 + 3) * 6 + j];
        }
        for (int k2 = 0; k2 < 32; k2 += 4) {
          float4 pr = *(const float4*)(sm + OFF_PR + (gg * 32 + k2) * 4);
          s += pr.x * p.qself_W[(64 + k2) * 6 + j];
          s += pr.y * p.qself_W[(65 + k2) * 6 + j];
          s += pr.z * p.qself_W[(66 + k2) * 6 + j];
          s += pr.w * p.qself_W[(67 + k2) * 6 + j];
        }
        p.out[be * 26 + j] = s;
      } else if (j >= 6 && j < 26) {
        int en = j - 6;
        float s = p.qint_b[0];
        const int t1off = OFF_T1 + (gg * 33 + 1 + en) * 144;
        for (int k2 = 0; k2 < 64; k2 += 4) {
          uint2 w = *(const uint2*)(sm + t1off + k2 * 2);
          s += bf2f((short)w.x) * p.qint_W[k2];
          s += bf2f((short)(w.x >> 16)) * p.qint_W[k2 + 1];
          s += bf2f((short)w.y) * p.qint_W[k2 + 2];
          s += bf2f((short)(w.y >> 16)) * p.qint_W[k2 + 3];
        }
        for (int k2 = 0; k2 < 32; k2 += 4) {
          float4 pr = *(const float4*)(sm + OFF_PR + (gg * 32 + k2) * 4);
          s += pr.x * p.qint_W[64 + k2];
          s += pr.y * p.qint_W[65 + k2];
          s += pr.z * p.qint_W[66 + k2];
          s += pr.w * p.qint_W[67 + k2];
        }
        p.out[be * 26 + 6 + en] = s;
      } else if (j >= 32 && j < 96) {
        int c = j - 32;
        p.out[(size_t)BTOT * 26 + be * 64 + c] =
            bf2f(LD16(sm, OFF_T1 + (gg * 33 + 32) * 144 + c * 2));
      }
    }
  }
}

// ---------------- fallback: round-1 fp32 kernel (proven) ----------------
#define TIN 32
#define TDIM 32
#define T 33
#define E 64
#define NH 4
#define NDEPTH 2

struct FParams {
  const float *inputs, *hidden, *p_h, *emb_W, *emb_b;
  const float *Wq, *Wk, *Wv, *Wu, *bu, *ln1_g, *ln1_b;
  const float *ff_W1, *ff_b1, *ff_W2, *ff_b2, *ln2_g, *ln2_b;
  const float *toprobs_W, *toprobs_b;
  const float *cls_W1, *cls_b1, *cls_W2, *cls_b2, *cls_W3, *cls_b3;
  const float *qself_W, *qself_b, *qint_W, *qint_b, *p_e_w;
  float* out;
};

__global__ __launch_bounds__(256) void fused_fb(FParams p) {
  const int b = blockIdx.x;
  const int tid = threadIdx.x;
  const int lane = tid & 63;
  const int wvv = tid >> 6;

  __shared__ float xb[T * E], t0[T * E], kT[E * T], vbuf[T * E], ab[T * E],
      scb[T * T];
  __shared__ float zz1[128], zz2[64], pbs[8], prs[32], phb[32];

  for (int idx = tid; idx < TIN * TDIM; idx += 256)
    scb[idx] = p.inputs[(size_t)b * TIN * TDIM + idx];
  if (tid < 32) phb[tid] = p.p_h[(size_t)b * 32 + tid];
  __syncthreads();
  {
    float s[8];
#pragma unroll
    for (int j = 0; j < 8; ++j) s[j] = 0.f;
    for (int k = 0; k < TDIM; ++k) {
      float w = p.emb_W[k * E + lane];
#pragma unroll
      for (int j = 0; j < 8; ++j) s[j] += scb[(wvv + 4 * j) * TDIM + k] * w;
    }
    float eb = p.emb_b[lane];
#pragma unroll
    for (int j = 0; j < 8; ++j) xb[(wvv + 4 * j) * E + lane] = s[j] + eb;
    if (wvv == 0) xb[32 * E + lane] = p.hidden[(size_t)b * E + lane];
  }
  __syncthreads();
  const float scale = SCL;
  for (int i = 0; i < NDEPTH; ++i) {
    {
      float bv = p.bu[i * E + lane];
#pragma unroll
      for (int j = 0; j < 9; ++j) {
        int r = wvv + 4 * j;
        if (j < 8 || wvv == 0) ab[r * E + lane] = bv;
      }
    }
    __syncthreads();
    for (int h = 0; h < NH; ++h) {
      const size_t qko = (size_t)i * E * 256 + h * E;
      {
        float sq[9], sk[9], sv[9];
#pragma unroll
        for (int j = 0; j < 9; ++j) { sq[j] = 0; sk[j] = 0; sv[j] = 0; }
        for (int k = 0; k < E; ++k) {
          float wq = p.Wq[qko + k * 256 + lane];
          float wk = p.Wk[qko + k * 256 + lane];
          float wvl = p.Wv[qko + k * 256 + lane];
#pragma unroll
          for (int j = 0; j < 9; ++j) {
            int r = wvv + 4 * j; if (r > 32) r = 32;
            float xv = xb[r * E + k];
            sq[j] += xv * wq; sk[j] += xv * wk; sv[j] += xv * wvl;
          }
        }
#pragma unroll
        for (int j = 0; j < 9; ++j) {
          int r = wvv + 4 * j;
          if (j < 8 || wvv == 0) {
            t0[r * E + lane] = sq[j] * scale;
            kT[lane * T + r] = sk[j] * scale;
            vbuf[r * E + lane] = sv[j];
          }
        }
      }
      __syncthreads();
      if (lane < T) {
        for (int qi = wvv; qi < T; qi += 4) {
          float s = 0.f;
          for (int e = 0; e < E; ++e) s += t0[qi * E + e] * kT[e * T + lane];
          scb[qi * T + lane] = s;
        }
      }
      __syncthreads();
      if (tid < T) {
        float m = -1e30f;
        for (int k2 = 0; k2 < T; ++k2) m = fmaxf(m, scb[tid * T + k2]);
        float sum = 0.f;
        for (int k2 = 0; k2 < T; ++k2) {
          float ev = __expf(scb[tid * T + k2] - m);
          scb[tid * T + k2] = ev; sum += ev;
        }
        float inv = 1.f / sum;
        for (int k2 = 0; k2 < T; ++k2) scb[tid * T + k2] *= inv;
      }
      __syncthreads();
      {
        float s[9];
#pragma unroll
        for (int j = 0; j < 9; ++j) s[j] = 0.f;
        for (int k2 = 0; k2 < T; ++k2) {
          float vload = vbuf[k2 * E + lane];
#pragma unroll
          for (int j = 0; j < 9; ++j) {
            int r = wvv + 4 * j; if (r > 32) r = 32;
            s[j] += scb[r * T + k2] * vload;
          }
        }
#pragma unroll
        for (int j = 0; j < 9; ++j) {
          int r = wvv + 4 * j;
          if (j < 8 || wvv == 0) t0[r * E + lane] = s[j];
        }
      }
      __syncthreads();
      {
        const size_t wuo = (size_t)i * 256 * 64 + (size_t)h * 64 * 64;
        float s[9];
#pragma unroll
        for (int j = 0; j < 9; ++j) s[j] = 0.f;
        for (int k2 = 0; k2 < E; ++k2) {
          float w = p.Wu[wuo + k2 * 64 + lane];
#pragma unroll
          for (int j = 0; j < 9; ++j) {
            int r = wvv + 4 * j; if (r > 32) r = 32;
            s[j] += t0[r * E + k2] * w;
          }
        }
#pragma unroll
        for (int j = 0; j < 9; ++j) {
          int r = wvv + 4 * j;
          if (j < 8 || wvv == 0) ab[r * E + lane] += s[j];
        }
      }
      __syncthreads();
    }
    {
      float gg = p.ln1_g[i * E + lane], bb = p.ln1_b[i * E + lane];
      for (int r = wvv; r < T; r += 4) {
        float v = ab[r * E + lane] + xb[r * E + lane];
        float s = v;
#pragma unroll
        for (int o = 32; o >= 1; o >>= 1) s += __shfl_xor(s, o, 64);
        float mu = s * (1.f / 64.f);
        float d = v - mu, q2 = d * d;
#pragma unroll
        for (int o = 32; o >= 1; o >>= 1) q2 += __shfl_xor(q2, o, 64);
        xb[r * E + lane] = d * (1.f / sqrtf(q2 * (1.f / 64.f) + 1e-5f)) * gg + bb;
      }
    }
    __syncthreads();
    {
      float bv = p.ff_b2[i * E + lane];
#pragma unroll
      for (int j = 0; j < 9; ++j) {
        int r = wvv + 4 * j;
        if (j < 8 || wvv == 0) ab[r * E + lane] = bv;
      }
    }
    __syncthreads();
    for (int cc = 0; cc < 4; ++cc) {
      {
        const size_t w1o = (size_t)i * E * 256 + cc * 64;
        float b1 = p.ff_b1[i * 256 + cc * 64 + lane];
        float s[9];
#pragma unroll
        for (int j = 0; j < 9; ++j) s[j] = b1;
        for (int k = 0; k < E; ++k) {
          float w = p.ff_W1[w1o + k * 256 + lane];
#pragma unroll
          for (int j = 0; j < 9; ++j) {
            int r = wvv + 4 * j; if (r > 32) r = 32;
            s[j] += xb[r * E + k] * w;
          }
        }
#pragma unroll
        for (int j = 0; j < 9; ++j) {
          int r = wvv + 4 * j;
          if (j < 8 || wvv == 0) t0[r * E + lane] = fmaxf(s[j], 0.f);
        }
      }
      __syncthreads();
      {
        const size_t w2o = (size_t)i * 256 * 64 + (size_t)cc * 64 * 64;
        float s[9];
#pragma unroll
        for (int j = 0; j < 9; ++j) s[j] = 0.f;
        for (int k = 0; k < E; ++k) {
          float w = p.ff_W2[w2o + k * 64 + lane];
#pragma unroll
          for (int j = 0; j < 9; ++j) {
            int r = wvv + 4 * j; if (r > 32) r = 32;
            s[j] += t0[r * E + k] * w;
          }
        }
#pragma unroll
        for (int j = 0; j < 9; ++j) {
          int r = wvv + 4 * j;
          if (j < 8 || wvv == 0) ab[r * E + lane] += s[j];
        }
      }
      __syncthreads();
    }
    {
      float gg = p.ln2_g[i * E + lane], bb = p.ln2_b[i * E + lane];
      for (int r = wvv; r < T; r += 4) {
        float v = ab[r * E + lane] + xb[r * E + lane];
        float s = v;
#pragma unroll
        for (int o = 32; o >= 1; o >>= 1) s += __shfl_xor(s, o, 64);
        float mu = s * (1.f / 64.f);
        float d = v - mu, q2 = d * d;
#pragma unroll
        for (int o = 32; o >= 1; o >>= 1) q2 += __shfl_xor(q2, o, 64);
        xb[r * E + lane] = d * (1.f / sqrtf(q2 * (1.f / 64.f) + 1e-5f)) * gg + bb;
      }
    }
    __syncthreads();
  }
  {
    float tb = p.toprobs_b[lane];
    float s[9];
#pragma unroll
    for (int j = 0; j < 9; ++j) s[j] = tb;
    for (int k = 0; k < E; ++k) {
      float w = p.toprobs_W[k * E + lane];
#pragma unroll
      for (int j = 0; j < 9; ++j) {
        int r = wvv + 4 * j; if (r > 32) r = 32;
        s[j] += xb[r * E + k] * w;
      }
    }
#pragma unroll
    for (int j = 0; j < 9; ++j) {
      int r = wvv + 4 * j;
      if (j < 8 || wvv == 0) t0[r * E + lane] = s[j];
    }
  }
  __syncthreads();
  if (tid < 128) {
    float s = p.cls_b1[tid];
    for (int k = 0; k < E; ++k) s += t0[32 * E + k] * p.cls_W1[k * 128 + tid];
    for (int k = 0; k < 32; ++k) s += phb[k] * p.cls_W1[(E + k) * 128 + tid];
    zz1[tid] = fmaxf(s, 0.f);
  }
  __syncthreads();
  if (tid < 64) {
    float s = p.cls_b2[tid];
    for (int k = 0; k < 128; ++k) s += zz1[k] * p.cls_W2[k * 64 + tid];
    zz2[tid] = fmaxf(s, 0.f);
  }
  __syncthreads();
  if (tid < 8) {
    float s = p.cls_b3[tid];
    for (int k = 0; k < 64; ++k) s += zz2[k] * p.cls_W3[k * 8 + tid];
    pbs[tid] = s;
  }
  __syncthreads();
  if (tid == 0) {
    float m = pbs[0];
#pragma unroll
    for (int k = 1; k < 8; ++k) m = fmaxf(m, pbs[k]);
    float e8[8], sum = 0.f;
#pragma unroll
    for (int k = 0; k < 8; ++k) { e8[k] = __expf(pbs[k] - m); sum += e8[k]; }
    float inv = 1.f / sum;
#pragma unroll
    for (int k = 0; k < 8; ++k) pbs[k] = e8[k] * inv;
  }
  __syncthreads();
  if (tid < 32) {
    float s = 0.f;
#pragma unroll
    for (int k = 0; k < 8; ++k) s += pbs[k] * p.p_e_w[k * 32 + tid];
    prs[tid] = s;
    p.out[(size_t)BTOT * 90 + (size_t)b * 32 + tid] = s;
    p.out[(size_t)BTOT * 122 + (size_t)b * 32 + tid] = s;
  }
  __syncthreads();
  if (tid < 6) {
    float s = p.qself_b[tid];
    for (int k = 0; k < E; ++k) s += t0[k] * p.qself_W[k * 6 + tid];
    for (int k = 0; k < 32; ++k) s += prs[k] * p.qself_W[(E + k) * 6 + tid];
    p.out[(size_t)b * 26 + tid] = s;
  }
  if (tid >= 64 && tid < 84) {
    int en = tid - 64;
    float s = p.qint_b[0];
    for (int k = 0; k < E; ++k) s += t0[(1 + en) * E + k] * p.qint_W[k];
    for (int k = 0; k < 32; ++k) s += prs[k] * p.qint_W[E + k];
    p.out[(size_t)b * 26 + 6 + en] = s;
  }
  if (tid >= 128 && tid < 192) {
    int c2 = tid - 128;
    p.out[(size_t)BTOT * 26 + (size_t)b * 64 + c2] = t0[32 * E + c2];
  }
}

extern "C" void kernel_launch(void* const* d_in, const int* in_sizes, int n_in,
                              void* d_out, int out_size, void* d_ws,
                              size_t ws_size, hipStream_t stream) {
  (void)in_sizes; (void)n_in; (void)out_size;
  if (ws_size >= (size_t)WS_BYTES) {
    PP pp;
    pp.emb = (const float*)d_in[3];
    pp.wq = (const float*)d_in[5];
    pp.wk = (const float*)d_in[6];
    pp.wvp = (const float*)d_in[7];
    pp.wu = (const float*)d_in[8];
    pp.w1 = (const float*)d_in[12];
    pp.w2 = (const float*)d_in[14];
    pp.top = (const float*)d_in[18];
    pp.dst = (short*)d_ws;
    hipLaunchKernelGGL(prep_frags, dim3(128), dim3(256), 0, stream, pp);

    MP p;
    p.inputs = (const float*)d_in[0];
    p.hidden = (const float*)d_in[1];
    p.p_h = (const float*)d_in[2];
    p.emb_b = (const float*)d_in[4];
    p.bu = (const float*)d_in[9];
    p.ln1_g = (const float*)d_in[10];
    p.ln1_b = (const float*)d_in[11];
    p.ff_b1 = (const float*)d_in[13];
    p.ff_b2 = (const float*)d_in[15];
    p.ln2_g = (const float*)d_in[16];
    p.ln2_b = (const float*)d_in[17];
    p.toprobs_b = (const float*)d_in[19];
    p.cls_W1 = (const float*)d_in[20];
    p.cls_b1 = (const float*)d_in[21];
    p.cls_W2 = (const float*)d_in[22];
    p.cls_b2 = (const float*)d_in[23];
    p.cls_W3 = (const float*)d_in[24];
    p.cls_b3 = (const float*)d_in[25];
    p.qself_W = (const float*)d_in[26];
    p.qself_b = (const float*)d_in[27];
    p.qint_W = (const float*)d_in[28];
    p.qint_b = (const float*)d_in[29];
    p.p_e_w = (const float*)d_in[30];
    p.ws = (const bf16x8*)d_ws;
    p.out = (float*)d_out;
    hipLaunchKernelGGL(fused_mfma, dim3(BTOT / 2), dim3(512), 0, stream, p);
  } else {
    FParams p;
    p.inputs = (const float*)d_in[0];
    p.hidden = (const float*)d_in[1];
    p.p_h = (const float*)d_in[2];
    p.emb_W = (const float*)d_in[3];
    p.emb_b = (const float*)d_in[4];
    p.Wq = (const float*)d_in[5];
    p.Wk = (const float*)d_in[6];
    p.Wv = (const float*)d_in[7];
    p.Wu = (const float*)d_in[8];
    p.bu = (const float*)d_in[9];
    p.ln1_g = (const float*)d_in[10];
    p.ln1_b = (const float*)d_in[11];
    p.ff_W1 = (const float*)d_in[12];
    p.ff_b1 = (const float*)d_in[13];
    p.ff_W2 = (const float*)d_in[14];
    p.ff_b2 = (const float*)d_in[15];
    p.ln2_g = (const float*)d_in[16];
    p.ln2_b = (const float*)d_in[17];
    p.toprobs_W = (const float*)d_in[18];
    p.toprobs_b = (const float*)d_in[19];
    p.cls_W1 = (const float*)d_in[20];
    p.cls_b1 = (const float*)d_in[21];
    p.cls_W2 = (const float*)d_in[22];
    p.cls_b2 = (const float*)d_in[23];
    p.cls_W3 = (const float*)d_in[24];
    p.cls_b3 = (const float*)d_in[25];
    p.qself_W = (const float*)d_in[26];
    p.qself_b = (const float*)d_in[27];
    p.qint_W = (const float*)d_in[28];
    p.qint_b = (const float*)d_in[29];
    p.p_e_w = (const float*)d_in[30];
    p.out = (float*)d_out;
    hipLaunchKernelGGL(fused_fb, dim3(BTOT), dim3(256), 0, stream, p);
  }
}

// Round 12
// 486.111 us; speedup vs baseline: 2.3586x; 1.0020x over previous
//
#include <hip/hip_runtime.h>
#include <hip/hip_bf16.h>
#include <stdint.h>

// PhaseUPDeT fused forward — round 14: epilogue parallelization (safe lever).
// Base = 487 µs anchor, main loop byte-identical. The epilogue ran with only
// 256 (later <=52) of 512 threads; waves 4-7 idled at barriers. cls1 (96
// MACs/thread) and cls2 (128 MACs/thread) are now split across all 512
// threads with WAVE-UNIFORM partitions (tid>>8 / tid>>7 — intra-wave splits
// would diverge and serialize) + LDS partial reduce in the dead Q buffer
// (zero LDS growth). Epilogue registers are scalar; attention-core peak
// pressure untouched -> no spill risk (tripwire: FETCH/WRITE unchanged).

typedef __hip_bfloat16 bf16;
using bf16x8 = __attribute__((ext_vector_type(8))) short;
using f32x4  = __attribute__((ext_vector_type(4))) float;
using s16x4  = __attribute__((ext_vector_type(4))) short;

#define BTOT 8192
#define SCL 0.35355339059327373f

// hand-rolled RNE (prep kernel only; runs once, perf-irrelevant)
__device__ __forceinline__ short f2bf(float f) {
  uint32_t u = __float_as_uint(f);
  return (short)((u + 0x7FFFu + ((u >> 16) & 1u)) >> 16);
}
__device__ __forceinline__ float bf2f(short s) {
  return __uint_as_float(((uint32_t)(uint16_t)s) << 16);
}
// f32 -> bf16 via official API: RNE, lowered by clang to the HW convert.
__device__ __forceinline__ short f2bfh(float f) {
  __hip_bfloat16 h = __float2bfloat16(f);
  return *reinterpret_cast<short*>(&h);
}
__device__ __forceinline__ f32x4 MM(bf16x8 a, bf16x8 b, f32x4 c) {
  return __builtin_amdgcn_mfma_f32_16x16x32_bf16(a, b, c, 0, 0, 0);
}

// ---------------- LDS layout (bytes) ----------------
#define OFF_X   0
#define OFF_Q   11520
#define OFF_K   23184
#define OFF_VT  34848
#define OFF_V32 45088
#define OFF_P   45344
#define OFF_T1  34848
#define OFF_ZZ1 46368
#define OFF_ZZ2 47392
#define OFF_PB  47904
#define OFF_PR  47968
#define OFF_PHB 53024
#define SMEM_SZ 53280
// epilogue partial-sum scratch inside the dead Q buffer
#define OFF_EP1 11520
#define OFF_EP2 13568

// ws fragment-slot offsets (units of bf16x8 = 8 elems)
#define WS_EMB 0
#define WS_WQ  256
#define WS_WK  4352
#define WS_WV  8448
#define WS_WU  12544
#define WS_W1  16640
#define WS_W2  20736
#define WS_TOP 24832
#define WS_BYTES 405504

__device__ __forceinline__ bf16x8 LD8(const uint8_t* sm, int off) {
  return *(const bf16x8*)(sm + off);
}
__device__ __forceinline__ void ST16(uint8_t* sm, int off, short v) {
  *(short*)(sm + off) = v;
}
__device__ __forceinline__ short LD16(const uint8_t* sm, int off) {
  return *(const short*)(sm + off);
}

// ---------------- prep kernel ----------------
struct PP {
  const float *emb, *wq, *wk, *wvp, *wu, *w1, *w2, *top;
  short* dst;
};

__global__ __launch_bounds__(256) void prep_frags(PP pp) {
  constexpr int START[15] = {0, 2048, 18432, 34816, 51200, 67584, 83968,
                             100352, 116736, 133120, 149504, 165888, 182272,
                             198656, 202752};
  for (int idx = blockIdx.x * 256 + threadIdx.x; idx < 202752;
       idx += gridDim.x * 256) {
#pragma unroll
    for (int t = 0; t < 14; ++t) {
      if (idx >= START[t] && idx < START[t + 1]) {
        int K, N; const float* s; float sc = 1.0f;
        switch (t) {
          case 0:  s = pp.emb;          K = 32;  N = 64;  break;
          case 1:  s = pp.wq;           K = 64;  N = 256; sc = SCL; break;
          case 2:  s = pp.wq + 16384;   K = 64;  N = 256; sc = SCL; break;
          case 3:  s = pp.wk;           K = 64;  N = 256; sc = SCL; break;
          case 4:  s = pp.wk + 16384;   K = 64;  N = 256; sc = SCL; break;
          case 5:  s = pp.wvp;          K = 64;  N = 256; break;
          case 6:  s = pp.wvp + 16384;  K = 64;  N = 256; break;
          case 7:  s = pp.wu;           K = 256; N = 64;  break;
          case 8:  s = pp.wu + 16384;   K = 256; N = 64;  break;
          case 9:  s = pp.w1;           K = 64;  N = 256; break;
          case 10: s = pp.w1 + 16384;   K = 64;  N = 256; break;
          case 11: s = pp.w2;           K = 256; N = 64;  break;
          case 12: s = pp.w2 + 16384;   K = 256; N = 64;  break;
          default: s = pp.top;          K = 64;  N = 64;  break;
        }
        int rel = idx - START[t];
        int lane = (rel >> 3) & 63, jj = rel & 7, fi = rel >> 9;
        int KS = K >> 5;
        int nt = fi / KS, ks = fi - nt * KS;
        int k = ks * 32 + ((lane >> 4) << 3) + jj;
        int n = nt * 16 + (lane & 15);
        pp.dst[idx] = f2bf(s[(size_t)k * N + n] * sc);
      }
    }
  }
}

// ---------------- main kernel ----------------
struct MP {
  const float *inputs, *hidden, *p_h;
  const float *emb_b, *bu, *ln1_g, *ln1_b, *ff_b1, *ff_b2, *ln2_g, *ln2_b,
      *toprobs_b;
  const float *cls_W1, *cls_b1, *cls_W2, *cls_b2, *cls_W3, *cls_b3;
  const float *qself_W, *qself_b, *qint_W, *qint_b, *p_e_w;
  const bf16x8* ws;
  float* out;
};

__global__ __launch_bounds__(512, 4) void fused_mfma(MP p) {
  __shared__ __align__(16) uint8_t sm[SMEM_SZ];
  const int tid = threadIdx.x;
  const int lane = tid & 63;
  const int wv = tid >> 6;  // 0..7
  const int g16 = lane >> 4;
  const int l15 = lane & 15;
  const int b0 = blockIdx.x * 2;
  const bf16x8* WS = p.ws;

  // ---- stage p_h, inputs (bf16, stride 40 @ OFF_T1), hidden ----
  if (tid < 64) {
    *(float*)(sm + OFF_PHB + tid * 4) =
        p.p_h[(size_t)(b0 + (tid >> 5)) * 32 + (tid & 31)];
  }
  for (int idx = tid; idx < 2048; idx += 512) {
    int r = idx >> 5, c = idx & 31;
    ST16(sm, OFF_T1 + r * 80 + c * 2, f2bfh(p.inputs[(size_t)b0 * 1024 + idx]));
  }
  if (tid < 128) {
    int e = tid >> 6, c = tid & 63;
    ST16(sm, OFF_X + (e * 33 + 32) * 144 + c * 2,
         f2bfh(p.hidden[(size_t)(b0 + e) * 64 + c]));
  }
  __syncthreads();

  // ---- emb GEMM: 16 (mt,nt) units over 8 waves ----
  {
#pragma unroll
    for (int uu = 0; uu < 2; ++uu) {
      int u = wv * 2 + uu;
      int mt = u >> 2, nt = u & 3;
      int arow = mt * 16 + l15;
      bf16x8 a = LD8(sm, OFF_T1 + arow * 80 + g16 * 16);
      int col = nt * 16 + l15;
      float eb = p.emb_b[col];
      f32x4 acc = {eb, eb, eb, eb};
      acc = MM(a, WS[WS_EMB + nt * 64 + lane], acc);
#pragma unroll
      for (int i = 0; i < 4; ++i) {
        int r = mt * 16 + g16 * 4 + i;
        int grow = (r >> 5) * 33 + (r & 31);
        ST16(sm, OFF_X + grow * 144 + col * 2, f2bfh(acc[i]));
      }
    }
  }
  __syncthreads();

  // attention-core ownership: wave wv<6 owns (elem ea, M-tile mtl)
  const bool att = wv < 6;
  const int ea = wv & 1;
  const int mtl = wv >> 1;  // 0..2 when att
  const int e33 = ea * 33;

  for (int L = 0; L < 2; ++L) {
    const int wq8 = WS_WQ + L * 2048, wk8 = WS_WK + L * 2048,
              wv8 = WS_WV + L * 2048, wu8 = WS_WU + L * 2048,
              w18 = WS_W1 + L * 2048, w28 = WS_W2 + L * 2048;

    // Wu accumulators (persist across heads), init with bu
    f32x4 wu[4];
#pragma unroll
    for (int nt = 0; nt < 4; ++nt) {
      float bv = p.bu[L * 64 + nt * 16 + l15];
      wu[nt] = {bv, bv, bv, bv};
    }

    for (int h = 0; h < 4; ++h) {
      // ---- QKV for head h: flat split over 20 (mt,nt) pairs, 8 waves ----
      // SCL pre-folded into prep'd Wq/Wk fragments.
      for (int wid = wv; wid < 20; wid += 8) {
        int mt = wid >> 2, nt = wid & 3;
        int arow = mt * 16 + l15;
        bf16x8 a0 = LD8(sm, OFF_X + arow * 144 + g16 * 16);
        bf16x8 a1 = LD8(sm, OFF_X + arow * 144 + 64 + g16 * 16);
        int col = nt * 16 + l15;
        int rb = mt * 16 + g16 * 4;
        int f0 = (h * 4 + nt) * 2;
        f32x4 q = {0.f, 0.f, 0.f, 0.f}, k = q, v = q;
        q = MM(a0, WS[wq8 + f0 * 64 + lane], q);
        q = MM(a1, WS[wq8 + (f0 + 1) * 64 + lane], q);
        k = MM(a0, WS[wk8 + f0 * 64 + lane], k);
        k = MM(a1, WS[wk8 + (f0 + 1) * 64 + lane], k);
        v = MM(a0, WS[wv8 + f0 * 64 + lane], v);
        v = MM(a1, WS[wv8 + (f0 + 1) * 64 + lane], v);
#pragma unroll
        for (int i = 0; i < 4; ++i) {
          int r = rb + i;
          if (r < 66) {
            ST16(sm, OFF_Q + r * 144 + col * 2, f2bfh(q[i]));
            ST16(sm, OFF_K + r * 144 + col * 2, f2bfh(k[i]));
          }
        }
        // v transposed: VT[(e*64+col)][tok]; packed b64 on the aligned path
        if (rb <= 28) {  // e=0, toks rb..rb+3, 8B-aligned
          s16x4 pv = {f2bfh(v[0]), f2bfh(v[1]), f2bfh(v[2]), f2bfh(v[3])};
          *(s16x4*)(sm + OFF_VT + col * 80 + rb * 2) = pv;
        } else if (rb >= 36 && rb <= 60) {  // e=1, toks rb-33.. (2B-aligned)
          int vb = OFF_VT + (64 + col) * 80 + (rb - 33) * 2;
          ST16(sm, vb, f2bfh(v[0]));
          ST16(sm, vb + 2, f2bfh(v[1]));
          ST16(sm, vb + 4, f2bfh(v[2]));
          ST16(sm, vb + 6, f2bfh(v[3]));
        } else if (rb == 32) {  // r=32: e0 tok32 -> V32; r=33..35: e1 tok0..2
          ST16(sm, OFF_V32 + col * 2, f2bfh(v[0]));
          int vb = OFF_VT + (64 + col) * 80;
          ST16(sm, vb, f2bfh(v[1]));
          ST16(sm, vb + 2, f2bfh(v[2]));
          ST16(sm, vb + 4, f2bfh(v[3]));
        } else if (rb == 64) {  // r=64: e1 tok31; r=65: e1 tok32 -> V32
          ST16(sm, OFF_VT + (64 + col) * 80 + 31 * 2, f2bfh(v[0]));
          ST16(sm, OFF_V32 + (64 + col) * 2, f2bfh(v[1]));
        }
      }
      __syncthreads();

      if (att) {
        // ---- scores: one (ea, mtl) tile per wave ----
        f32x4 S[3];
        {
          int arow = e33 + mtl * 16 + l15;
          bf16x8 a0 = LD8(sm, OFF_Q + arow * 144 + g16 * 16);
          bf16x8 a1 = LD8(sm, OFF_Q + arow * 144 + 64 + g16 * 16);
#pragma unroll
          for (int nt = 0; nt < 3; ++nt) {
            int brow = e33 + nt * 16 + l15;
            bf16x8 kb0 = LD8(sm, OFF_K + brow * 144 + g16 * 16);
            bf16x8 kb1 = LD8(sm, OFF_K + brow * 144 + 64 + g16 * 16);
            f32x4 acc = {0.f, 0.f, 0.f, 0.f};
            acc = MM(a0, kb0, acc);
            acc = MM(a1, kb1, acc);
            S[nt] = acc;
          }
        }
        // ---- softmax, no-max variant (scores O(1); shift-invariant) ----
        // Store RAW exp to P; keep 1/sum in registers, applied after AV.
        float p32sav[4], invs[4];
#pragma unroll
        for (int i = 0; i < 4; ++i) {
          float p0 = __expf(S[0][i]);
          float p1 = __expf(S[1][i]);
          float p2 = (l15 == 0) ? __expf(S[2][i]) : 0.f;
          // stores depend only on exp — issue before the sum reduction
          int prow = ea * 48 + mtl * 16 + g16 * 4 + i;
          ST16(sm, OFF_P + prow * 80 + l15 * 2, f2bfh(p0));
          ST16(sm, OFF_P + prow * 80 + (16 + l15) * 2, f2bfh(p1));
          float s = p0 + p1 + p2;
          s += __shfl_xor(s, 1, 64);
          s += __shfl_xor(s, 2, 64);
          s += __shfl_xor(s, 4, 64);
          s += __shfl_xor(s, 8, 64);
          invs[i] = 1.0f / s;
          p32sav[i] = __shfl(p2, lane & 48, 64);
        }
        asm volatile("s_waitcnt lgkmcnt(0)" ::: "memory");
        // ---- AV (K=32 MFMA) + key-32 rank-1; normalize; write attn ----
        {
          bf16x8 pa =
              LD8(sm, OFF_P + (ea * 48 + mtl * 16 + l15) * 80 + g16 * 16);
#pragma unroll
          for (int nt = 0; nt < 4; ++nt) {
            int col = nt * 16 + l15;
            float v32v = bf2f(LD16(sm, OFF_V32 + (ea * 64 + col) * 2));
            bf16x8 vb = LD8(sm, OFF_VT + (ea * 64 + col) * 80 + g16 * 16);
            f32x4 acc = {0.f, 0.f, 0.f, 0.f};
            acc = MM(pa, vb, acc);
#pragma unroll
            for (int i = 0; i < 4; ++i) {
              float o = (acc[i] + p32sav[i] * v32v) * invs[i];
              int lr = mtl * 16 + g16 * 4 + i;
              if (lr < 33)
                ST16(sm, OFF_Q + (e33 + lr) * 144 + col * 2, f2bfh(o));
            }
          }
        }
        asm volatile("s_waitcnt lgkmcnt(0)" ::: "memory");
        // ---- Wu accumulate (K=64 slice of Wu at rows h*64..) ----
        {
          int arow = e33 + mtl * 16 + l15;
          bf16x8 a0 = LD8(sm, OFF_Q + arow * 144 + g16 * 16);
          bf16x8 a1 = LD8(sm, OFF_Q + arow * 144 + 64 + g16 * 16);
#pragma unroll
          for (int nt = 0; nt < 4; ++nt) {
            wu[nt] = MM(a0, WS[wu8 + (nt * 8 + h * 2) * 64 + lane], wu[nt]);
            wu[nt] =
                MM(a1, WS[wu8 + (nt * 8 + h * 2 + 1) * 64 + lane], wu[nt]);
          }
        }
      }
      __syncthreads();
    }  // heads

    // ---- LN1 in-register (wave's owned rows) ----
    if (att) {
#pragma unroll
      for (int i = 0; i < 4; ++i) {
        int lr = mtl * 16 + g16 * 4 + i;
        int grow = e33 + lr;
        bool ok = (lr < 33);
        float v[4];
#pragma unroll
        for (int nt = 0; nt < 4; ++nt) {
          int col = nt * 16 + l15;
          float xr = ok ? bf2f(LD16(sm, OFF_X + grow * 144 + col * 2)) : 0.f;
          v[nt] = wu[nt][i] + xr;
        }
        float s = v[0] + v[1] + v[2] + v[3];
        s += __shfl_xor(s, 1, 64); s += __shfl_xor(s, 2, 64);
        s += __shfl_xor(s, 4, 64); s += __shfl_xor(s, 8, 64);
        float mu = s * 0.015625f;
        float q2 = 0.f;
#pragma unroll
        for (int nt = 0; nt < 4; ++nt) { float d = v[nt] - mu; q2 += d * d; }
        q2 += __shfl_xor(q2, 1, 64); q2 += __shfl_xor(q2, 2, 64);
        q2 += __shfl_xor(q2, 4, 64); q2 += __shfl_xor(q2, 8, 64);
        float inv = rsqrtf(q2 * 0.015625f + 1e-5f);
#pragma unroll
        for (int nt = 0; nt < 4; ++nt) {
          int col = nt * 16 + l15;
          float o = (v[nt] - mu) * inv * p.ln1_g[L * 64 + col] +
                    p.ln1_b[L * 64 + col];
          if (ok) ST16(sm, OFF_X + grow * 144 + col * 2, f2bfh(o));
        }
      }
    }
    __syncthreads();

    // ---- FF (5 M-tiles, one per wave wv<5; same-wave t1 produce/consume) ----
    f32x4 ff[4];
#pragma unroll
    for (int nt = 0; nt < 4; ++nt) {
      float bv = p.ff_b2[L * 64 + nt * 16 + l15];
      ff[nt] = {bv, bv, bv, bv};
    }
    const bool ffw = wv < 5;
    const int fmt = wv;
#pragma unroll
    for (int cc = 0; cc < 4; ++cc) {
      if (ffw) {
        int arow = fmt * 16 + l15;
        bf16x8 a0 = LD8(sm, OFF_X + arow * 144 + g16 * 16);
        bf16x8 a1 = LD8(sm, OFF_X + arow * 144 + 64 + g16 * 16);
#pragma unroll
        for (int nt = 0; nt < 4; ++nt) {
          float b1 = p.ff_b1[L * 256 + cc * 64 + nt * 16 + l15];
          f32x4 hh = {b1, b1, b1, b1};
          int f0 = (cc * 4 + nt) * 2;
          hh = MM(a0, WS[w18 + f0 * 64 + lane], hh);
          hh = MM(a1, WS[w18 + (f0 + 1) * 64 + lane], hh);
#pragma unroll
          for (int i = 0; i < 4; ++i)
            ST16(sm,
                 OFF_T1 + (fmt * 16 + g16 * 4 + i) * 144 + (nt * 16 + l15) * 2,
                 f2bfh(fmaxf(hh[i], 0.f)));
        }
        asm volatile("s_waitcnt lgkmcnt(0)" ::: "memory");
        bf16x8 ta = LD8(sm, OFF_T1 + arow * 144 + g16 * 16);
        bf16x8 tb = LD8(sm, OFF_T1 + arow * 144 + 64 + g16 * 16);
#pragma unroll
        for (int nt = 0; nt < 4; ++nt) {
          ff[nt] = MM(ta, WS[w28 + (nt * 8 + cc * 2) * 64 + lane], ff[nt]);
          ff[nt] = MM(tb, WS[w28 + (nt * 8 + cc * 2 + 1) * 64 + lane], ff[nt]);
        }
      }
    }
    // ---- LN2 in-register (wave's fmt rows) ----
    if (ffw) {
#pragma unroll
      for (int i = 0; i < 4; ++i) {
        int grow = fmt * 16 + g16 * 4 + i;
        bool ok = grow < 66;
        float v[4];
#pragma unroll
        for (int nt = 0; nt < 4; ++nt) {
          int col = nt * 16 + l15;
          float xr = ok ? bf2f(LD16(sm, OFF_X + grow * 144 + col * 2)) : 0.f;
          v[nt] = ff[nt][i] + xr;
        }
        float s = v[0] + v[1] + v[2] + v[3];
        s += __shfl_xor(s, 1, 64); s += __shfl_xor(s, 2, 64);
        s += __shfl_xor(s, 4, 64); s += __shfl_xor(s, 8, 64);
        float mu = s * 0.015625f;
        float q2 = 0.f;
#pragma unroll
        for (int nt = 0; nt < 4; ++nt) { float d = v[nt] - mu; q2 += d * d; }
        q2 += __shfl_xor(q2, 1, 64); q2 += __shfl_xor(q2, 2, 64);
        q2 += __shfl_xor(q2, 4, 64); q2 += __shfl_xor(q2, 8, 64);
        float inv = rsqrtf(q2 * 0.015625f + 1e-5f);
#pragma unroll
        for (int nt = 0; nt < 4; ++nt) {
          int col = nt * 16 + l15;
          float o = (v[nt] - mu) * inv * p.ln2_g[L * 64 + col] +
                    p.ln2_b[L * 64 + col];
          if (ok) ST16(sm, OFF_X + grow * 144 + col * 2, f2bfh(o));
        }
      }
    }
    __syncthreads();
  }  // layers

  // ---- toprobs -> t1 (bf16): flat split over 20 (mt,nt) pairs ----
  for (int wid = wv; wid < 20; wid += 8) {
    int mt = wid >> 2, nt = wid & 3;
    int arow = mt * 16 + l15;
    bf16x8 a0 = LD8(sm, OFF_X + arow * 144 + g16 * 16);
    bf16x8 a1 = LD8(sm, OFF_X + arow * 144 + 64 + g16 * 16);
    int col = nt * 16 + l15;
    float tb = p.toprobs_b[col];
    f32x4 acc = {tb, tb, tb, tb};
    acc = MM(a0, WS[WS_TOP + (nt * 2) * 64 + lane], acc);
    acc = MM(a1, WS[WS_TOP + (nt * 2 + 1) * 64 + lane], acc);
#pragma unroll
    for (int i = 0; i < 4; ++i) {
      int r = mt * 16 + g16 * 4 + i;
      ST16(sm, OFF_T1 + r * 144 + col * 2, f2bfh(acc[i]));
    }
  }
  __syncthreads();

  // ---- epilogue (cls1/cls2 parallelized over all 512 threads) ----
  {
    const bool act = tid < 256;
    const int gg = (tid >> 7) & 1;
    const int j = tid & 127;
    const size_t be = (size_t)(b0 + gg);
    // cls1: 2-way wave-uniform split (half = tid>>8); 48 MACs per thread
    {
      const int half = tid >> 8;       // 0..1, uniform per wave
      const int u = tid & 255;         // unit index
      const int ug = u >> 7, uj = u & 127;
      const int t1off = OFF_T1 + (ug * 33 + 32) * 144;
      float s = 0.f;
      if (half == 0) {
        for (int k2 = 0; k2 < 48; k2 += 4) {
          uint2 w = *(const uint2*)(sm + t1off + k2 * 2);
          s += bf2f((short)w.x) * p.cls_W1[k2 * 128 + uj];
          s += bf2f((short)(w.x >> 16)) * p.cls_W1[(k2 + 1) * 128 + uj];
          s += bf2f((short)w.y) * p.cls_W1[(k2 + 2) * 128 + uj];
          s += bf2f((short)(w.y >> 16)) * p.cls_W1[(k2 + 3) * 128 + uj];
        }
      } else {
        for (int k2 = 48; k2 < 64; k2 += 4) {
          uint2 w = *(const uint2*)(sm + t1off + k2 * 2);
          s += bf2f((short)w.x) * p.cls_W1[k2 * 128 + uj];
          s += bf2f((short)(w.x >> 16)) * p.cls_W1[(k2 + 1) * 128 + uj];
          s += bf2f((short)w.y) * p.cls_W1[(k2 + 2) * 128 + uj];
          s += bf2f((short)(w.y >> 16)) * p.cls_W1[(k2 + 3) * 128 + uj];
        }
        for (int k2 = 0; k2 < 32; k2 += 4) {
          float4 ph = *(const float4*)(sm + OFF_PHB + (ug * 32 + k2) * 4);
          s += ph.x * p.cls_W1[(64 + k2) * 128 + uj];
          s += ph.y * p.cls_W1[(65 + k2) * 128 + uj];
          s += ph.z * p.cls_W1[(66 + k2) * 128 + uj];
          s += ph.w * p.cls_W1[(67 + k2) * 128 + uj];
        }
      }
      *(float*)(sm + OFF_EP1 + (half * 256 + u) * 4) = s;
    }
    __syncthreads();
    if (act) {
      float s = p.cls_b1[j] + *(float*)(sm + OFF_EP1 + tid * 4) +
                *(float*)(sm + OFF_EP1 + (256 + tid) * 4);
      *(float*)(sm + OFF_ZZ1 + tid * 4) = fmaxf(s, 0.f);
    }
    __syncthreads();
    // cls2: 4-way wave-uniform split (quarter = tid>>7); 32 MACs per thread
    {
      const int qq = tid >> 7;         // 0..3, uniform per wave
      const int u = tid & 127;         // unit: ug2 = u>>6, uj2 = u&63
      const int ug2 = u >> 6, uj2 = u & 63;
      float s = 0.f;
      const int kbase = qq * 32;
      for (int k2 = kbase; k2 < kbase + 32; k2 += 4) {
        float4 z = *(const float4*)(sm + OFF_ZZ1 + (ug2 * 128 + k2) * 4);
        s += z.x * p.cls_W2[k2 * 64 + uj2];
        s += z.y * p.cls_W2[(k2 + 1) * 64 + uj2];
        s += z.z * p.cls_W2[(k2 + 2) * 64 + uj2];
        s += z.w * p.cls_W2[(k2 + 3) * 64 + uj2];
      }
      *(float*)(sm + OFF_EP2 + (qq * 128 + u) * 4) = s;
    }
    __syncthreads();
    if (tid < 128) {
      float s = p.cls_b2[tid & 63] + *(float*)(sm + OFF_EP2 + tid * 4) +
                *(float*)(sm + OFF_EP2 + (128 + tid) * 4) +
                *(float*)(sm + OFF_EP2 + (256 + tid) * 4) +
                *(float*)(sm + OFF_EP2 + (384 + tid) * 4);
      *(float*)(sm + OFF_ZZ2 + tid * 4) = fmaxf(s, 0.f);
    }
    __syncthreads();
    if (act && j < 8) {
      float s = p.cls_b3[j];
      for (int k2 = 0; k2 < 64; k2 += 4) {
        float4 z = *(const float4*)(sm + OFF_ZZ2 + (gg * 64 + k2) * 4);
        s += z.x * p.cls_W3[k2 * 8 + j];
        s += z.y * p.cls_W3[(k2 + 1) * 8 + j];
        s += z.z * p.cls_W3[(k2 + 2) * 8 + j];
        s += z.w * p.cls_W3[(k2 + 3) * 8 + j];
      }
      *(float*)(sm + OFF_PB + (gg * 8 + j) * 4) = s;
    }
    __syncthreads();
    if (act && j == 0) {
      float* pb = (float*)(sm + OFF_PB) + gg * 8;
      float m = pb[0];
#pragma unroll
      for (int k2 = 1; k2 < 8; ++k2) m = fmaxf(m, pb[k2]);
      float sum = 0.f, e8[8];
#pragma unroll
      for (int k2 = 0; k2 < 8; ++k2) {
        e8[k2] = __expf(pb[k2] - m);
        sum += e8[k2];
      }
      float inv = 1.f / sum;
#pragma unroll
      for (int k2 = 0; k2 < 8; ++k2) pb[k2] = e8[k2] * inv;
    }
    __syncthreads();
    if (act && j < 32) {
      float s = 0.f;
#pragma unroll
      for (int k2 = 0; k2 < 8; ++k2)
        s += *(float*)(sm + OFF_PB + (gg * 8 + k2) * 4) * p.p_e_w[k2 * 32 + j];
      *(float*)(sm + OFF_PR + (gg * 32 + j) * 4) = s;
      p.out[(size_t)BTOT * 90 + be * 32 + j] = s;
      p.out[(size_t)BTOT * 122 + be * 32 + j] = s;
    }
    __syncthreads();
    if (act) {
      if (j < 6) {
        float s = p.qself_b[j];
        const int t1off = OFF_T1 + (gg * 33) * 144;
        for (int k2 = 0; k2 < 64; k2 += 4) {
          uint2 w = *(const uint2*)(sm + t1off + k2 * 2);
          s += bf2f((short)w.x) * p.qself_W[k2 * 6 + j];
          s += bf2f((short)(w.x >> 16)) * p.qself_W[(k2 + 1) * 6 + j];
          s += bf2f((short)w.y) * p.qself_W[(k2 + 2) * 6 + j];
          s += bf2f((short)(w.y >> 16)) * p.qself_W[(k2 + 3) * 6 + j];
        }
        for (int k2 = 0; k2 < 32; k2 += 4) {
          float4 pr = *(const float4*)(sm + OFF_PR + (gg * 32 + k2) * 4);
          s += pr.x * p.qself_W[(64 + k2) * 6 + j];
          s += pr.y * p.qself_W[(65 + k2) * 6 + j];
          s += pr.z * p.qself_W[(66 + k2) * 6 + j];
          s += pr.w * p.qself_W[(67 + k2) * 6 + j];
        }
        p.out[be * 26 + j] = s;
      } else if (j >= 6 && j < 26) {
        int en = j - 6;
        float s = p.qint_b[0];
        const int t1off = OFF_T1 + (gg * 33 + 1 + en) * 144;
        for (int k2 = 0; k2 < 64; k2 += 4) {
          uint2 w = *(const uint2*)(sm + t1off + k2 * 2);
          s += bf2f((short)w.x) * p.qint_W[k2];
          s += bf2f((short)(w.x >> 16)) * p.qint_W[k2 + 1];
          s += bf2f((short)w.y) * p.qint_W[k2 + 2];
          s += bf2f((short)(w.y >> 16)) * p.qint_W[k2 + 3];
        }
        for (int k2 = 0; k2 < 32; k2 += 4) {
          float4 pr = *(const float4*)(sm + OFF_PR + (gg * 32 + k2) * 4);
          s += pr.x * p.qint_W[64 + k2];
          s += pr.y * p.qint_W[65 + k2];
          s += pr.z * p.qint_W[66 + k2];
          s += pr.w * p.qint_W[67 + k2];
        }
        p.out[be * 26 + 6 + en] = s;
      } else if (j >= 32 && j < 96) {
        int c = j - 32;
        p.out[(size_t)BTOT * 26 + be * 64 + c] =
            bf2f(LD16(sm, OFF_T1 + (gg * 33 + 32) * 144 + c * 2));
      }
    }
  }
}

// ---------------- fallback: round-1 fp32 kernel (proven) ----------------
#define TIN 32
#define TDIM 32
#define T 33
#define E 64
#define NH 4
#define NDEPTH 2

struct FParams {
  const float *inputs, *hidden, *p_h, *emb_W, *emb_b;
  const float *Wq, *Wk, *Wv, *Wu, *bu, *ln1_g, *ln1_b;
  const float *ff_W1, *ff_b1, *ff_W2, *ff_b2, *ln2_g, *ln2_b;
  const float *toprobs_W, *toprobs_b;
  const float *cls_W1, *cls_b1, *cls_W2, *cls_b2, *cls_W3, *cls_b3;
  const float *qself_W, *qself_b, *qint_W, *qint_b, *p_e_w;
  float* out;
};

__global__ __launch_bounds__(256) void fused_fb(FParams p) {
  const int b = blockIdx.x;
  const int tid = threadIdx.x;
  const int lane = tid & 63;
  const int wvv = tid >> 6;

  __shared__ float xb[T * E], t0[T * E], kT[E * T], vbuf[T * E], ab[T * E],
      scb[T * T];
  __shared__ float zz1[128], zz2[64], pbs[8], prs[32], phb[32];

  for (int idx = tid; idx < TIN * TDIM; idx += 256)
    scb[idx] = p.inputs[(size_t)b * TIN * TDIM + idx];
  if (tid < 32) phb[tid] = p.p_h[(size_t)b * 32 + tid];
  __syncthreads();
  {
    float s[8];
#pragma unroll
    for (int j = 0; j < 8; ++j) s[j] = 0.f;
    for (int k = 0; k < TDIM; ++k) {
      float w = p.emb_W[k * E + lane];
#pragma unroll
      for (int j = 0; j < 8; ++j) s[j] += scb[(wvv + 4 * j) * TDIM + k] * w;
    }
    float eb = p.emb_b[lane];
#pragma unroll
    for (int j = 0; j < 8; ++j) xb[(wvv + 4 * j) * E + lane] = s[j] + eb;
    if (wvv == 0) xb[32 * E + lane] = p.hidden[(size_t)b * E + lane];
  }
  __syncthreads();
  const float scale = SCL;
  for (int i = 0; i < NDEPTH; ++i) {
    {
      float bv = p.bu[i * E + lane];
#pragma unroll
      for (int j = 0; j < 9; ++j) {
        int r = wvv + 4 * j;
        if (j < 8 || wvv == 0) ab[r * E + lane] = bv;
      }
    }
    __syncthreads();
    for (int h = 0; h < NH; ++h) {
      const size_t qko = (size_t)i * E * 256 + h * E;
      {
        float sq[9], sk[9], sv[9];
#pragma unroll
        for (int j = 0; j < 9; ++j) { sq[j] = 0; sk[j] = 0; sv[j] = 0; }
        for (int k = 0; k < E; ++k) {
          float wq = p.Wq[qko + k * 256 + lane];
          float wk = p.Wk[qko + k * 256 + lane];
          float wvl = p.Wv[qko + k * 256 + lane];
#pragma unroll
          for (int j = 0; j < 9; ++j) {
            int r = wvv + 4 * j; if (r > 32) r = 32;
            float xv = xb[r * E + k];
            sq[j] += xv * wq; sk[j] += xv * wk; sv[j] += xv * wvl;
          }
        }
#pragma unroll
        for (int j = 0; j < 9; ++j) {
          int r = wvv + 4 * j;
          if (j < 8 || wvv == 0) {
            t0[r * E + lane] = sq[j] * scale;
            kT[lane * T + r] = sk[j] * scale;
            vbuf[r * E + lane] = sv[j];
          }
        }
      }
      __syncthreads();
      if (lane < T) {
        for (int qi = wvv; qi < T; qi += 4) {
          float s = 0.f;
          for (int e = 0; e < E; ++e) s += t0[qi * E + e] * kT[e * T + lane];
          scb[qi * T + lane] = s;
        }
      }
      __syncthreads();
      if (tid < T) {
        float m = -1e30f;
        for (int k2 = 0; k2 < T; ++k2) m = fmaxf(m, scb[tid * T + k2]);
        float sum = 0.f;
        for (int k2 = 0; k2 < T; ++k2) {
          float ev = __expf(scb[tid * T + k2] - m);
          scb[tid * T + k2] = ev; sum += ev;
        }
        float inv = 1.f / sum;
        for (int k2 = 0; k2 < T; ++k2) scb[tid * T + k2] *= inv;
      }
      __syncthreads();
      {
        float s[9];
#pragma unroll
        for (int j = 0; j < 9; ++j) s[j] = 0.f;
        for (int k2 = 0; k2 < T; ++k2) {
          float vload = vbuf[k2 * E + lane];
#pragma unroll
          for (int j = 0; j < 9; ++j) {
            int r = wvv + 4 * j; if (r > 32) r = 32;
            s[j] += scb[r * T + k2] * vload;
          }
        }
#pragma unroll
        for (int j = 0; j < 9; ++j) {
          int r = wvv + 4 * j;
          if (j < 8 || wvv == 0) t0[r * E + lane] = s[j];
        }
      }
      __syncthreads();
      {
        const size_t wuo = (size_t)i * 256 * 64 + (size_t)h * 64 * 64;
        float s[9];
#pragma unroll
        for (int j = 0; j < 9; ++j) s[j] = 0.f;
        for (int k2 = 0; k2 < E; ++k2) {
          float w = p.Wu[wuo + k2 * 64 + lane];
#pragma unroll
          for (int j = 0; j < 9; ++j) {
            int r = wvv + 4 * j; if (r > 32) r = 32;
            s[j] += t0[r * E + k2] * w;
          }
        }
#pragma unroll
        for (int j = 0; j < 9; ++j) {
          int r = wvv + 4 * j;
          if (j < 8 || wvv == 0) ab[r * E + lane] += s[j];
        }
      }
      __syncthreads();
    }
    {
      float gg = p.ln1_g[i * E + lane], bb = p.ln1_b[i * E + lane];
      for (int r = wvv; r < T; r += 4) {
        float v = ab[r * E + lane] + xb[r * E + lane];
        float s = v;
#pragma unroll
        for (int o = 32; o >= 1; o >>= 1) s += __shfl_xor(s, o, 64);
        float mu = s * (1.f / 64.f);
        float d = v - mu, q2 = d * d;
#pragma unroll
        for (int o = 32; o >= 1; o >>= 1) q2 += __shfl_xor(q2, o, 64);
        xb[r * E + lane] = d * (1.f / sqrtf(q2 * (1.f / 64.f) + 1e-5f)) * gg + bb;
      }
    }
    __syncthreads();
    {
      float bv = p.ff_b2[i * E + lane];
#pragma unroll
      for (int j = 0; j < 9; ++j) {
        int r = wvv + 4 * j;
        if (j < 8 || wvv == 0) ab[r * E + lane] = bv;
      }
    }
    __syncthreads();
    for (int cc = 0; cc < 4; ++cc) {
      {
        const size_t w1o = (size_t)i * E * 256 + cc * 64;
        float b1 = p.ff_b1[i * 256 + cc * 64 + lane];
        float s[9];
#pragma unroll
        for (int j = 0; j < 9; ++j) s[j] = b1;
        for (int k = 0; k < E; ++k) {
          float w = p.ff_W1[w1o + k * 256 + lane];
#pragma unroll
          for (int j = 0; j < 9; ++j) {
            int r = wvv + 4 * j; if (r > 32) r = 32;
            s[j] += xb[r * E + k] * w;
          }
        }
#pragma unroll
        for (int j = 0; j < 9; ++j) {
          int r = wvv + 4 * j;
          if (j < 8 || wvv == 0) t0[r * E + lane] = fmaxf(s[j], 0.f);
        }
      }
      __syncthreads();
      {
        const size_t w2o = (size_t)i * 256 * 64 + (size_t)cc * 64 * 64;
        float s[9];
#pragma unroll
        for (int j = 0; j < 9; ++j) s[j] = 0.f;
        for (int k = 0; k < E; ++k) {
          float w = p.ff_W2[w2o + k * 64 + lane];
#pragma unroll
          for (int j = 0; j < 9; ++j) {
            int r = wvv + 4 * j; if (r > 32) r = 32;
            s[j] += t0[r * E + k] * w;
          }
        }
#pragma unroll
        for (int j = 0; j < 9; ++j) {
          int r = wvv + 4 * j;
          if (j < 8 || wvv == 0) ab[r * E + lane] += s[j];
        }
      }
      __syncthreads();
    }
    {
      float gg = p.ln2_g[i * E + lane], bb = p.ln2_b[i * E + lane];
      for (int r = wvv; r < T; r += 4) {
        float v = ab[r * E + lane] + xb[r * E + lane];
        float s = v;
#pragma unroll
        for (int o = 32; o >= 1; o >>= 1) s += __shfl_xor(s, o, 64);
        float mu = s * (1.f / 64.f);
        float d = v - mu, q2 = d * d;
#pragma unroll
        for (int o = 32; o >= 1; o >>= 1) q2 += __shfl_xor(q2, o, 64);
        xb[r * E + lane] = d * (1.f / sqrtf(q2 * (1.f / 64.f) + 1e-5f)) * gg + bb;
      }
    }
    __syncthreads();
  }
  {
    float tb = p.toprobs_b[lane];
    float s[9];
#pragma unroll
    for (int j = 0; j < 9; ++j) s[j] = tb;
    for (int k = 0; k < E; ++k) {
      float w = p.toprobs_W[k * E + lane];
#pragma unroll
      for (int j = 0; j < 9; ++j) {
        int r = wvv + 4 * j; if (r > 32) r = 32;
        s[j] += xb[r * E + k] * w;
      }
    }
#pragma unroll
    for (int j = 0; j < 9; ++j) {
      int r = wvv + 4 * j;
      if (j < 8 || wvv == 0) t0[r * E + lane] = s[j];
    }
  }
  __syncthreads();
  if (tid < 128) {
    float s = p.cls_b1[tid];
    for (int k = 0; k < E; ++k) s += t0[32 * E + k] * p.cls_W1[k * 128 + tid];
    for (int k = 0; k < 32; ++k) s += phb[k] * p.cls_W1[(E + k) * 128 + tid];
    zz1[tid] = fmaxf(s, 0.f);
  }
  __syncthreads();
  if (tid < 64) {
    float s = p.cls_b2[tid];
    for (int k = 0; k < 128; ++k) s += zz1[k] * p.cls_W2[k * 64 + tid];
    zz2[tid] = fmaxf(s, 0.f);
  }
  __syncthreads();
  if (tid < 8) {
    float s = p.cls_b3[tid];
    for (int k = 0; k < 64; ++k) s += zz2[k] * p.cls_W3[k * 8 + tid];
    pbs[tid] = s;
  }
  __syncthreads();
  if (tid == 0) {
    float m = pbs[0];
#pragma unroll
    for (int k = 1; k < 8; ++k) m = fmaxf(m, pbs[k]);
    float e8[8], sum = 0.f;
#pragma unroll
    for (int k = 0; k < 8; ++k) { e8[k] = __expf(pbs[k] - m); sum += e8[k]; }
    float inv = 1.f / sum;
#pragma unroll
    for (int k = 0; k < 8; ++k) pbs[k] = e8[k] * inv;
  }
  __syncthreads();
  if (tid < 32) {
    float s = 0.f;
#pragma unroll
    for (int k = 0; k < 8; ++k) s += pbs[k] * p.p_e_w[k * 32 + tid];
    prs[tid] = s;
    p.out[(size_t)BTOT * 90 + (size_t)b * 32 + tid] = s;
    p.out[(size_t)BTOT * 122 + (size_t)b * 32 + tid] = s;
  }
  __syncthreads();
  if (tid < 6) {
    float s = p.qself_b[tid];
    for (int k = 0; k < E; ++k) s += t0[k] * p.qself_W[k * 6 + tid];
    for (int k = 0; k < 32; ++k) s += prs[k] * p.qself_W[(E + k) * 6 + tid];
    p.out[(size_t)b * 26 + tid] = s;
  }
  if (tid >= 64 && tid < 84) {
    int en = tid - 64;
    float s = p.qint_b[0];
    for (int k = 0; k < E; ++k) s += t0[(1 + en) * E + k] * p.qint_W[k];
    for (int k = 0; k < 32; ++k) s += prs[k] * p.qint_W[E + k];
    p.out[(size_t)b * 26 + 6 + en] = s;
  }
  if (tid >= 128 && tid < 192) {
    int c2 = tid - 128;
    p.out[(size_t)BTOT * 26 + (size_t)b * 64 + c2] = t0[32 * E + c2];
  }
}

extern "C" void kernel_launch(void* const* d_in, const int* in_sizes, int n_in,
                              void* d_out, int out_size, void* d_ws,
                              size_t ws_size, hipStream_t stream) {
  (void)in_sizes; (void)n_in; (void)out_size;
  if (ws_size >= (size_t)WS_BYTES) {
    PP pp;
    pp.emb = (const float*)d_in[3];
    pp.wq = (const float*)d_in[5];
    pp.wk = (const float*)d_in[6];
    pp.wvp = (const float*)d_in[7];
    pp.wu = (const float*)d_in[8];
    pp.w1 = (const float*)d_in[12];
    pp.w2 = (const float*)d_in[14];
    pp.top = (const float*)d_in[18];
    pp.dst = (short*)d_ws;
    hipLaunchKernelGGL(prep_frags, dim3(128), dim3(256), 0, stream, pp);

    MP p;
    p.inputs = (const float*)d_in[0];
    p.hidden = (const float*)d_in[1];
    p.p_h = (const float*)d_in[2];
    p.emb_b = (const float*)d_in[4];
    p.bu = (const float*)d_in[9];
    p.ln1_g = (const float*)d_in[10];
    p.ln1_b = (const float*)d_in[11];
    p.ff_b1 = (const float*)d_in[13];
    p.ff_b2 = (const float*)d_in[15];
    p.ln2_g = (const float*)d_in[16];
    p.ln2_b = (const float*)d_in[17];
    p.toprobs_b = (const float*)d_in[19];
    p.cls_W1 = (const float*)d_in[20];
    p.cls_b1 = (const float*)d_in[21];
    p.cls_W2 = (const float*)d_in[22];
    p.cls_b2 = (const float*)d_in[23];
    p.cls_W3 = (const float*)d_in[24];
    p.cls_b3 = (const float*)d_in[25];
    p.qself_W = (const float*)d_in[26];
    p.qself_b = (const float*)d_in[27];
    p.qint_W = (const float*)d_in[28];
    p.qint_b = (const float*)d_in[29];
    p.p_e_w = (const float*)d_in[30];
    p.ws = (const bf16x8*)d_ws;
    p.out = (float*)d_out;
    hipLaunchKernelGGL(fused_mfma, dim3(BTOT / 2), dim3(512), 0, stream, p);
  } else {
    FParams p;
    p.inputs = (const float*)d_in[0];
    p.hidden = (const float*)d_in[1];
    p.p_h = (const float*)d_in[2];
    p.emb_W = (const float*)d_in[3];
    p.emb_b = (const float*)d_in[4];
    p.Wq = (const float*)d_in[5];
    p.Wk = (const float*)d_in[6];
    p.Wv = (const float*)d_in[7];
    p.Wu = (const float*)d_in[8];
    p.bu = (const float*)d_in[9];
    p.ln1_g = (const float*)d_in[10];
    p.ln1_b = (const float*)d_in[11];
    p.ff_W1 = (const float*)d_in[12];
    p.ff_b1 = (const float*)d_in[13];
    p.ff_W2 = (const float*)d_in[14];
    p.ff_b2 = (const float*)d_in[15];
    p.ln2_g = (const float*)d_in[16];
    p.ln2_b = (const float*)d_in[17];
    p.toprobs_W = (const float*)d_in[18];
    p.toprobs_b = (const float*)d_in[19];
    p.cls_W1 = (const float*)d_in[20];
    p.cls_b1 = (const float*)d_in[21];
    p.cls_W2 = (const float*)d_in[22];
    p.cls_b2 = (const float*)d_in[23];
    p.cls_W3 = (const float*)d_in[24];
    p.cls_b3 = (const float*)d_in[25];
    p.qself_W = (const float*)d_in[26];
    p.qself_b = (const float*)d_in[27];
    p.qint_W = (const float*)d_in[28];
    p.qint_b = (const float*)d_in[29];
    p.p_e_w = (const float*)d_in[30];
    p.out = (float*)d_out;
    hipLaunchKernelGGL(fused_fb, dim3(BTOT), dim3(256), 0, stream, p);
  }
}